// Round 2
// baseline (385.146 us; speedup 1.0000x reference)
//
#include <hip/hip_runtime.h>
#include <hip/hip_bf16.h>

#define BB 2
#define HH 12
#define SS 4096
#define DD 768
#define HD 64
#define NBK 64
#define MC 3

typedef __attribute__((ext_vector_type(8))) short short8_t;
typedef __attribute__((ext_vector_type(4))) float float4_t;

__device__ __forceinline__ unsigned short f2bf(float f) {
  union { float f; unsigned u; } c;
  c.f = f;
  unsigned u = c.u + 0x7FFFu + ((c.u >> 16) & 1u);  // RNE
  return (unsigned short)(u >> 16);
}

// async 16B global -> LDS (gfx950). LDS dest = wave-uniform base + lane*16.
__device__ __forceinline__ void gload16(const unsigned short* gp,
                                        unsigned short* lp) {
  __builtin_amdgcn_global_load_lds(
      (const __attribute__((address_space(1))) unsigned int*)gp,
      (__attribute__((address_space(3))) unsigned int*)lp, 16, 0, 0);
}

#define LDK 72  // padded stride (attn kernel only)

// ---------------------------------------------------------------------------
// One-shot fp32 -> bf16 conversion: hs (8192x768), Wq|Wk|Wv packed (2304x768),
// Wo (768x768). One float4 per thread.
// ---------------------------------------------------------------------------
__global__ __launch_bounds__(256) void cvt_all(
    const float* __restrict__ hs, const float* __restrict__ Wq,
    const float* __restrict__ Wk, const float* __restrict__ Wv,
    const float* __restrict__ Wo, unsigned short* __restrict__ hsb,
    unsigned short* __restrict__ wqkvb, unsigned short* __restrict__ wob) {
  long i4 = (long)blockIdx.x * 256 + threadIdx.x;  // float4 index
  const float* src;
  unsigned short* dst;
  if (i4 < 1572864) {          // hs: 6291456 floats
    src = hs + i4 * 4;
    dst = hsb + i4 * 4;
  } else {
    long r = i4 - 1572864;
    int w = (int)(r / 147456);  // 0..3 : Wq,Wk,Wv,Wo (589824 floats each)
    long e = r % 147456;
    src = (w == 0 ? Wq : w == 1 ? Wk : w == 2 ? Wv : Wo) + e * 4;
    dst = (w < 3) ? (wqkvb + (long)w * 589824 + e * 4) : (wob + e * 4);
  }
  float4_t v = *(const float4_t*)src;
  uint2 p;
  p.x = (unsigned)f2bf(v[0]) | ((unsigned)f2bf(v[1]) << 16);
  p.y = (unsigned)f2bf(v[2]) | ((unsigned)f2bf(v[3]) << 16);
  *(uint2*)dst = p;
}

// ---------------------------------------------------------------------------
// GEMM, 2-phase structure, BK=32: LDS = 32 KB/block -> 5 blocks/CU resident
// (latency hidden by cross-block TLP, m114 mechanism). 24 K-iters.
// LDS row = 32 shorts = 4 chunks of 16B. Swizzle: global chunk c of row r
// sits in slot c ^ (r&3) ^ ((r>>2)&3)  (2-bit XOR; leaves only free 2-way
// bank aliasing on ds_read_b128 at 64B row stride).
// Single barrier per K-iter: prefetch of kt+32 issues AFTER the barrier,
// stays in flight during compute, drains at the NEXT barrier.
// ---------------------------------------------------------------------------
#define STAGE32(buf_, A_, B_, m0_, n0_, kt_)                                  \
  {                                                                           \
    _Pragma("unroll") for (int u = 0; u < 2; u++) {                           \
      int g_ = w * 2 + u;                                                     \
      gload16(A_ + (size_t)(m0_ + g_ * 16 + r16) * DD + (kt_) + cg * 8,       \
              &As[buf_][g_ * 512]);                                           \
      gload16(B_ + (size_t)(n0_ + g_ * 16 + r16) * DD + (kt_) + cg * 8,       \
              &Bs[buf_][g_ * 512]);                                           \
    }                                                                         \
  }

#define FRAGS32(buf_)                                                         \
  short8_t af[4], bfr[4];                                                     \
  _Pragma("unroll") for (int i = 0; i < 4; i++)                               \
      af[i] = *(const short8_t*)&As[buf_][(wm + i * 16 + fr) * 32 +           \
                                          (qd ^ sxor) * 8];                   \
  _Pragma("unroll") for (int j = 0; j < 4; j++)                               \
      bfr[j] = *(const short8_t*)&Bs[buf_][(wn + j * 16 + fr) * 32 +          \
                                           (qd ^ sxor) * 8];

// ---------------------------------------------------------------------------
// QKV projection, bf16 inputs, dbuf async staging, 1 barrier/iter.
// Q/K tiles: SWAPPED operands (C^T, reg dim spans d) -> packed uint2 stores.
// V: normal orientation (reg dim spans s) -> packed uint2 stores transposed.
// ---------------------------------------------------------------------------
__global__ __launch_bounds__(256, 5) void gemm_qkv_b(
    const unsigned short* __restrict__ A, const unsigned short* __restrict__ W,
    unsigned short* __restrict__ qb, unsigned short* __restrict__ kb,
    unsigned short* __restrict__ vtb) {
  __shared__ unsigned short As[2][128 * 32];  // 16 KB
  __shared__ unsigned short Bs[2][128 * 32];  // 16 KB
  int tid = threadIdx.x;
  int m0 = blockIdx.x * 128;
  int n0 = blockIdx.y * 128;  // 0..2176, never straddles a 768 boundary
  int lane = tid & 63;
  int w = tid >> 6;
  int wm = (w >> 1) * 64;
  int wn = (w & 1) * 64;
  int fr = lane & 15;
  int qd = lane >> 4;
  int sxor = (fr & 3) ^ ((fr >> 2) & 3);
  int r16 = lane >> 2;                                  // staging row 0..15
  int cg = (lane & 3) ^ ((r16 & 3) ^ ((r16 >> 2) & 3)); // staged global chunk
  int ysel = n0 / 768;

  float4_t acc[4][4];
#pragma unroll
  for (int i = 0; i < 4; i++)
#pragma unroll
    for (int j = 0; j < 4; j++)
#pragma unroll
      for (int r = 0; r < 4; r++) acc[i][j][r] = 0.f;

  STAGE32(0, A, W, m0, n0, 0)
  int p = 0;

  if (ysel < 2) {
    // ---- Q/K: swapped-operand K-loop; acc[j][i] = C^T tile ----
    for (int kt = 0; kt < DD; kt += 32) {
      __syncthreads();  // drains stage(kt); waves done reading buf p^1
      if (kt + 32 < DD) STAGE32(p ^ 1, A, W, m0, n0, kt + 32)
      FRAGS32(p)
#pragma unroll
      for (int i = 0; i < 4; i++)
#pragma unroll
        for (int j = 0; j < 4; j++)
          acc[j][i] = __builtin_amdgcn_mfma_f32_16x16x32_bf16(
              bfr[j], af[i], acc[j][i], 0, 0, 0);
      p ^= 1;
    }
    int cn = lane & 15;
    int quad = lane >> 4;
    float scale = (ysel == 0) ? 0.125f : 1.0f;  // fold 1/sqrt(64) into Q
    unsigned short* dst = (ysel == 0) ? qb : kb;
    int nb0 = n0 - ysel * 768;
#pragma unroll
    for (int j = 0; j < 4; j++)
#pragma unroll
      for (int i = 0; i < 4; i++) {
        int m = m0 + wm + i * 16 + cn;            // s dimension
        int nn = nb0 + wn + j * 16 + quad * 4;    // d dimension (4-consec)
        int b = m >> 12, s = m & 4095;
        int h = nn >> 6, d0 = nn & 63;
        uint2 pk;
        pk.x = (unsigned)f2bf(acc[j][i][0] * scale) |
               ((unsigned)f2bf(acc[j][i][1] * scale) << 16);
        pk.y = (unsigned)f2bf(acc[j][i][2] * scale) |
               ((unsigned)f2bf(acc[j][i][3] * scale) << 16);
        *(uint2*)&dst[(((size_t)b * HH + h) * SS + s) * HD + d0] = pk;
      }
  } else {
    // ---- V: normal K-loop; reg dim spans s (contig in [b][h][d][s]) ----
    for (int kt = 0; kt < DD; kt += 32) {
      __syncthreads();
      if (kt + 32 < DD) STAGE32(p ^ 1, A, W, m0, n0, kt + 32)
      FRAGS32(p)
#pragma unroll
      for (int i = 0; i < 4; i++)
#pragma unroll
        for (int j = 0; j < 4; j++)
          acc[i][j] = __builtin_amdgcn_mfma_f32_16x16x32_bf16(
              af[i], bfr[j], acc[i][j], 0, 0, 0);
      p ^= 1;
    }
    int cn = lane & 15;
    int quad = lane >> 4;
    int nb0 = n0 - 1536;
#pragma unroll
    for (int i = 0; i < 4; i++)
#pragma unroll
      for (int j = 0; j < 4; j++) {
        int m = m0 + wm + i * 16 + quad * 4;      // s base (4-consec)
        int nn = nb0 + wn + j * 16 + cn;          // d dimension
        int b = m >> 12, s0 = m & 4095;
        int h = nn >> 6, d = nn & 63;
        uint2 pk;
        pk.x = (unsigned)f2bf(acc[i][j][0]) |
               ((unsigned)f2bf(acc[i][j][1]) << 16);
        pk.y = (unsigned)f2bf(acc[i][j][2]) |
               ((unsigned)f2bf(acc[i][j][3]) << 16);
        *(uint2*)&vtb[(((size_t)b * HH + h) * HD + d) * SS + s0] = pk;
      }
  }
}

// ---------------------------------------------------------------------------
// Output projection, bf16 inputs, fp32 output (coalesced), same BK=32 dbuf.
// ---------------------------------------------------------------------------
__global__ __launch_bounds__(256, 5) void gemm_out_b(
    const unsigned short* __restrict__ A, const unsigned short* __restrict__ W,
    float* __restrict__ dst) {
  __shared__ unsigned short As[2][128 * 32];
  __shared__ unsigned short Bs[2][128 * 32];
  int tid = threadIdx.x;
  int m0 = blockIdx.x * 128;
  int n0 = blockIdx.y * 128;
  int lane = tid & 63;
  int w = tid >> 6;
  int wm = (w >> 1) * 64;
  int wn = (w & 1) * 64;
  int fr = lane & 15;
  int qd = lane >> 4;
  int sxor = (fr & 3) ^ ((fr >> 2) & 3);
  int r16 = lane >> 2;
  int cg = (lane & 3) ^ ((r16 & 3) ^ ((r16 >> 2) & 3));

  float4_t acc[4][4];
#pragma unroll
  for (int i = 0; i < 4; i++)
#pragma unroll
    for (int j = 0; j < 4; j++)
#pragma unroll
      for (int r = 0; r < 4; r++) acc[i][j][r] = 0.f;

  STAGE32(0, A, W, m0, n0, 0)
  int p = 0;
  for (int kt = 0; kt < DD; kt += 32) {
    __syncthreads();
    if (kt + 32 < DD) STAGE32(p ^ 1, A, W, m0, n0, kt + 32)
    FRAGS32(p)
#pragma unroll
    for (int i = 0; i < 4; i++)
#pragma unroll
      for (int j = 0; j < 4; j++)
        acc[i][j] = __builtin_amdgcn_mfma_f32_16x16x32_bf16(
            af[i], bfr[j], acc[i][j], 0, 0, 0);
    p ^= 1;
  }

  int cn = lane & 15;
  int rb = (lane >> 4) * 4;
#pragma unroll
  for (int i = 0; i < 4; i++)
#pragma unroll
    for (int j = 0; j < 4; j++)
#pragma unroll
      for (int r = 0; r < 4; r++) {
        int m = m0 + wm + i * 16 + rb + r;
        int n = n0 + wn + j * 16 + cn;
        dst[(size_t)m * DD + n] = acc[i][j][r];
      }
}

// ---------------------------------------------------------------------------
// Block-sparse attention, fixed-max softmax, dbuf K/V LDS, 1 barrier/iter.
// Heavy blocks (l=0,63) split 8 ways -> partial O + rowsum to scratch.
// Grid: ids 0..383 heavy chunks, 384..1871 lights.
// ---------------------------------------------------------------------------
__global__ __launch_bounds__(256) void attn2(
    const unsigned short* __restrict__ q, const unsigned short* __restrict__ k,
    const unsigned short* __restrict__ vt, const int* __restrict__ graph,
    unsigned short* __restrict__ ctxb, float* __restrict__ part) {
  __shared__ unsigned short Ks[2][64 * LDK];   // K[key][d]
  __shared__ unsigned short Vs[2][64 * LDK];   // V^T[d][key]
  __shared__ unsigned short Ps[4][16 * LDK];   // per-wave P[q][key]

  int tid = threadIdx.x;
  int id = blockIdx.x;
  int b, h, l, nkb, heavy, chunk = 0, hid = 0;
  int list[8];
  if (id < 384) {
    heavy = 1;
    hid = id >> 3;
    chunk = id & 7;
    b = hid / 24;
    int r = hid % 24;
    h = r >> 1;
    l = (r & 1) ? (NBK - 1) : 0;
    nkb = 8;
#pragma unroll
    for (int i = 0; i < 8; i++) list[i] = chunk * 8 + i;
  } else {
    heavy = 0;
    int j = id - 384;
    b = j / 744;  // 744 = 12*62
    int r = j % 744;
    h = r / 62;
    l = 1 + r % 62;
    const int* g = graph + (((size_t)b * HH + h) * NBK + l) * MC;
    int n = 0;
    if (l == 1) {
      list[0] = 0; list[1] = 1; list[2] = 2; list[3] = NBK - 1; n = 4;
    } else if (l == NBK - 2) {
      list[0] = 0; list[1] = NBK - 3; list[2] = NBK - 2; list[3] = NBK - 1; n = 4;
    } else {
      list[0] = 0; list[1] = l - 1; list[2] = l; list[3] = l + 1;
      list[4] = NBK - 1; n = 5;
    }
    for (int m = 0; m < MC; m++) list[n++] = g[m];
    nkb = n;
  }
  size_t base = ((size_t)b * HH + h) * SS * HD;

  int lane = tid & 63;
  int w = tid >> 6;
  int lr = lane & 15;     // fragment m/n index
  int quad = lane >> 4;   // fragment k-group

  // Q fragments (A-layout) straight from global into registers (q pre-scaled).
  short8_t qa[2];
  {
    const unsigned short* qp =
        q + base + (size_t)(l * 64 + w * 16 + lr) * HD + quad * 8;
    qa[0] = *(const short8_t*)qp;
    qa[1] = *(const short8_t*)(qp + 32);
  }

  float4_t Ot[4];
  float ls[4];  // per-lane partial row sums (4 cols/row this lane)
#pragma unroll
  for (int t = 0; t < 4; t++)
#pragma unroll
    for (int r = 0; r < 4; r++) Ot[t][r] = 0.f;
#pragma unroll
  for (int r = 0; r < 4; r++) ls[r] = 0.f;

  // staging: each thread moves 2x16B for K and 2x16B for Vt
  int srow = tid >> 3;          // 0..31
  int scol = (tid & 7) * 8;     // 0..56

  uint4 kr0, kr1, vr0, vr1;
  {
    int kb = list[0];
    const unsigned short* kp = k + base + (size_t)(kb * 64 + srow) * HD + scol;
    const unsigned short* vp = vt + base + (size_t)srow * SS + kb * 64 + scol;
    kr0 = *(const uint4*)kp;
    kr1 = *(const uint4*)(kp + 32 * HD);
    vr0 = *(const uint4*)vp;
    vr1 = *(const uint4*)(vp + 32 * SS);
  }
  // write block 0 into buf 0
  *(uint4*)&Ks[0][srow * LDK + scol] = kr0;
  *(uint4*)&Ks[0][(srow + 32) * LDK + scol] = kr1;
  *(uint4*)&Vs[0][srow * LDK + scol] = vr0;
  *(uint4*)&Vs[0][(srow + 32) * LDK + scol] = vr1;
  int p = 0;

  for (int t = 0; t < nkb; t++) {
    __syncthreads();  // buf[p] writes visible; all waves done reading buf[p^1]

    if (t + 1 < nkb) {  // issue next block's global loads (fly during compute)
      int kb = list[t + 1];
      const unsigned short* kp = k + base + (size_t)(kb * 64 + srow) * HD + scol;
      const unsigned short* vp = vt + base + (size_t)srow * SS + kb * 64 + scol;
      kr0 = *(const uint4*)kp;
      kr1 = *(const uint4*)(kp + 32 * HD);
      vr0 = *(const uint4*)vp;
      vr1 = *(const uint4*)(vp + 32 * SS);
    }

    // S = Q K^T
    float4_t st[4];
#pragma unroll
    for (int tt = 0; tt < 4; tt++) {
#pragma unroll
      for (int r = 0; r < 4; r++) st[tt][r] = 0.f;
      short8_t kb0 = *(const short8_t*)&Ks[p][(tt * 16 + lr) * LDK + quad * 8];
      short8_t kb1 =
          *(const short8_t*)&Ks[p][(tt * 16 + lr) * LDK + quad * 8 + 32];
      st[tt] = __builtin_amdgcn_mfma_f32_16x16x32_bf16(qa[0], kb0, st[tt], 0, 0, 0);
      st[tt] = __builtin_amdgcn_mfma_f32_16x16x32_bf16(qa[1], kb1, st[tt], 0, 0, 0);
    }

    // fixed-max softmax: p = exp(s); per-lane partial sums, no shuffles.
#pragma unroll
    for (int tt = 0; tt < 4; tt++)
#pragma unroll
      for (int r = 0; r < 4; r++) {
        float pv = __expf(st[tt][r]);
        st[tt][r] = pv;
        ls[r] += pv;
        Ps[w][(quad * 4 + r) * LDK + tt * 16 + lr] = f2bf(pv);
      }

    // O += P V
#pragma unroll
    for (int s = 0; s < 2; s++) {
      short8_t pa = *(const short8_t*)&Ps[w][lr * LDK + s * 32 + quad * 8];
#pragma unroll
      for (int tt = 0; tt < 4; tt++) {
        short8_t vb =
            *(const short8_t*)&Vs[p][(tt * 16 + lr) * LDK + s * 32 + quad * 8];
        Ot[tt] = __builtin_amdgcn_mfma_f32_16x16x32_bf16(pa, vb, Ot[tt], 0, 0, 0);
      }
    }

    if (t + 1 < nkb) {  // write prefetched regs into the other buffer
      *(uint4*)&Ks[p ^ 1][srow * LDK + scol] = kr0;
      *(uint4*)&Ks[p ^ 1][(srow + 32) * LDK + scol] = kr1;
      *(uint4*)&Vs[p ^ 1][srow * LDK + scol] = vr0;
      *(uint4*)&Vs[p ^ 1][(srow + 32) * LDK + scol] = vr1;
    }
    p ^= 1;
  }

  // reduce row sums across the 16 lanes holding each row
#pragma unroll
  for (int r = 0; r < 4; r++)
#pragma unroll
    for (int off = 1; off < 16; off <<= 1) ls[r] += __shfl_xor(ls[r], off);

  if (!heavy) {
#pragma unroll
    for (int r = 0; r < 4; r++) {
      float inv = 1.f / ls[r];
      size_t row = (size_t)b * SS + (size_t)l * 64 + w * 16 + quad * 4 + r;
#pragma unroll
      for (int tt = 0; tt < 4; tt++)
        ctxb[row * DD + h * HD + tt * 16 + lr] = f2bf(Ot[tt][r] * inv);
    }
  } else {
    float* pb = part + ((size_t)hid * 8 + chunk) * 4160;  // 64*64 O + 64 lsum
#pragma unroll
    for (int r = 0; r < 4; r++) {
      int rowi = w * 16 + quad * 4 + r;
#pragma unroll
      for (int tt = 0; tt < 4; tt++)
        pb[rowi * 64 + tt * 16 + lr] = Ot[tt][r];
      if (lr == 0) pb[4096 + rowi] = ls[r];
    }
  }
}

// ---------------------------------------------------------------------------
// Combine the 8 partials of each heavy block, normalize, write bf16 ctx.
// ---------------------------------------------------------------------------
__global__ __launch_bounds__(256) void reduce_heavy(
    const float* __restrict__ part, unsigned short* __restrict__ ctxb) {
  __shared__ float lrow[64];
  int hid = blockIdx.x;
  int tid = threadIdx.x;
  int b = hid / 24;
  int r = hid % 24;
  int h = r >> 1;
  int l = (r & 1) ? (NBK - 1) : 0;
  const float* pb = part + (size_t)hid * 8 * 4160;
  if (tid < 64) {
    float s = 0.f;
#pragma unroll
    for (int c = 0; c < 8; c++) s += pb[c * 4160 + 4096 + tid];
    lrow[tid] = s;
  }
  __syncthreads();
#pragma unroll
  for (int e = tid; e < 4096; e += 256) {
    float o = 0.f;
#pragma unroll
    for (int c = 0; c < 8; c++) o += pb[c * 4160 + e];
    int rowi = e >> 6, col = e & 63;
    size_t row = (size_t)b * SS + (size_t)l * 64 + rowi;
    ctxb[row * DD + h * HD + col] = f2bf(o / lrow[rowi]);
  }
}

extern "C" void kernel_launch(void* const* d_in, const int* in_sizes, int n_in,
                              void* d_out, int out_size, void* d_ws,
                              size_t ws_size, hipStream_t stream) {
  const float* hs = (const float*)d_in[0];
  const float* Wq = (const float*)d_in[1];
  const float* Wk = (const float*)d_in[2];
  const float* Wv = (const float*)d_in[3];
  const float* Wo = (const float*)d_in[4];
  const int* graph = (const int*)d_in[10];

  const size_t NHS = (size_t)BB * SS * DD;  // 6291456
  unsigned short* hsb = (unsigned short*)d_ws;
  unsigned short* wqkvb = hsb + NHS;            // 3*768*768
  unsigned short* wob = wqkvb + 3 * 768 * 768;  // 768*768
  unsigned short* qb = wob + 768 * 768;
  unsigned short* kb = qb + NHS;
  unsigned short* vtb = kb + NHS;
  unsigned short* ctxb = vtb + NHS;
  float* part = (float*)(ctxb + NHS);  // 48*8*4160 floats

  cvt_all<<<8448, 256, 0, stream>>>(hs, Wq, Wk, Wv, Wo, hsb, wqkvb, wob);
  gemm_qkv_b<<<dim3(64, 18, 1), 256, 0, stream>>>(hsb, wqkvb, qb, kb, vtb);
  attn2<<<1872, 256, 0, stream>>>(qb, kb, vtb, graph, ctxb, part);
  reduce_heavy<<<48, 256, 0, stream>>>(part, ctxb);
  gemm_out_b<<<dim3(64, 6, 1), 256, 0, stream>>>(ctxb, wob, (float*)d_out);
}

// Round 3
// 260.420 us; speedup vs baseline: 1.4789x; 1.4789x over previous
//
#include <hip/hip_runtime.h>
#include <hip/hip_bf16.h>

#define BB 2
#define HH 12
#define SS 4096
#define DD 768
#define HD 64
#define NBK 64
#define MC 3

typedef __attribute__((ext_vector_type(8))) short short8_t;
typedef __attribute__((ext_vector_type(4))) float float4_t;

__device__ __forceinline__ unsigned short f2bf(float f) {
  union { float f; unsigned u; } c;
  c.f = f;
  unsigned u = c.u + 0x7FFFu + ((c.u >> 16) & 1u);  // RNE
  return (unsigned short)(u >> 16);
}

// async 16B global -> LDS (gfx950). LDS dest = wave-uniform base + lane*16.
__device__ __forceinline__ void gload16(const unsigned short* gp,
                                        unsigned short* lp) {
  __builtin_amdgcn_global_load_lds(
      (const __attribute__((address_space(1))) unsigned int*)gp,
      (__attribute__((address_space(3))) unsigned int*)lp, 16, 0, 0);
}

#define LDK 72  // padded stride (attn kernel only)

// ---------------------------------------------------------------------------
// One-shot fp32 -> bf16 conversion: hs (8192x768), Wq|Wk|Wv packed (2304x768),
// Wo (768x768). One float4 per thread.
// ---------------------------------------------------------------------------
__global__ __launch_bounds__(256) void cvt_all(
    const float* __restrict__ hs, const float* __restrict__ Wq,
    const float* __restrict__ Wk, const float* __restrict__ Wv,
    const float* __restrict__ Wo, unsigned short* __restrict__ hsb,
    unsigned short* __restrict__ wqkvb, unsigned short* __restrict__ wob) {
  long i4 = (long)blockIdx.x * 256 + threadIdx.x;  // float4 index
  const float* src;
  unsigned short* dst;
  if (i4 < 1572864) {          // hs: 6291456 floats
    src = hs + i4 * 4;
    dst = hsb + i4 * 4;
  } else {
    long r = i4 - 1572864;
    int w = (int)(r / 147456);  // 0..3 : Wq,Wk,Wv,Wo (589824 floats each)
    long e = r % 147456;
    src = (w == 0 ? Wq : w == 1 ? Wk : w == 2 ? Wv : Wo) + e * 4;
    dst = (w < 3) ? (wqkvb + (long)w * 589824 + e * 4) : (wob + e * 4);
  }
  float4_t v = *(const float4_t*)src;
  uint2 p;
  p.x = (unsigned)f2bf(v[0]) | ((unsigned)f2bf(v[1]) << 16);
  p.y = (unsigned)f2bf(v[2]) | ((unsigned)f2bf(v[3]) << 16);
  *(uint2*)dst = p;
}

// ---------------------------------------------------------------------------
// GEMM helpers. A: double-buffered XOR-swizzled LDS (32 KB total -> 4
// blocks/CU at __launch_bounds__(256,4)). B (weights): NOT staged — panels
// are L2-resident (3.5 MB total, shared by 64 blocks each); fragments are
// read directly from global per K-step and hidden under MFMA + cross-block
// TLP. Single barrier per K-iter: A-prefetch of kt+64 issues AFTER the
// barrier, flies during compute, drains at the NEXT barrier.
// LDS row r = 64 shorts (8 chunks of 16B); global chunk c at slot c^(r&7).
// ---------------------------------------------------------------------------
#define STAGE_A(buf_, A_, m0_, kt_)                                           \
  {                                                                           \
    int rr_ = lane >> 3;                                                      \
    int cg_ = (lane & 7) ^ rr_;                                               \
    _Pragma("unroll") for (int u = 0; u < 4; u++) {                           \
      int g_ = w * 4 + u;                                                     \
      gload16(A_ + (size_t)(m0_ + g_ * 8 + rr_) * DD + kt_ + cg_ * 8,         \
              &As[buf_][g_ * 512]);                                           \
    }                                                                         \
  }

#define LOAD_FRAGS_AB(buf_, kt_, kk_)                                         \
  int cb = qd + ((kk_) >> 3);                                                 \
  short8_t af[4], bfr[4];                                                     \
  _Pragma("unroll") for (int i = 0; i < 4; i++) {                             \
    int r_ = wm + i * 16 + fr;                                                \
    af[i] = *(const short8_t*)&As[buf_][r_ * 64 + (cb ^ (fr & 7)) * 8];       \
  }                                                                           \
  _Pragma("unroll") for (int j = 0; j < 4; j++)                               \
    bfr[j] = *(const short8_t*)&Wg[(size_t)(j * 16) * DD + (kt_) + (kk_)];

// ---------------------------------------------------------------------------
// QKV projection, bf16 inputs, A staged via gload_lds, B direct from L2.
// Q/K tiles: SWAPPED operands (C^T, reg dim spans d) -> packed uint2 stores.
// V: normal orientation (reg dim spans s) -> packed uint2 stores transposed.
// ---------------------------------------------------------------------------
__global__ __launch_bounds__(256, 4) void gemm_qkv_b(
    const unsigned short* __restrict__ A, const unsigned short* __restrict__ W,
    unsigned short* __restrict__ qb, unsigned short* __restrict__ kb,
    unsigned short* __restrict__ vtb) {
  __shared__ unsigned short As[2][128 * 64];  // 32 KB
  int tid = threadIdx.x;
  int m0 = blockIdx.x * 128;
  int n0 = blockIdx.y * 128;  // 0..2176, never straddles a 768 boundary
  int lane = tid & 63;
  int w = tid >> 6;
  int wm = (w >> 1) * 64;
  int wn = (w & 1) * 64;
  int fr = lane & 15;
  int qd = lane >> 4;
  int ysel = n0 / 768;
  // per-lane base into the B (weights) panel: row n0+wn+fr, col qd*8
  const unsigned short* Wg = W + (size_t)(n0 + wn + fr) * DD + qd * 8;

  float4_t acc[4][4];
#pragma unroll
  for (int i = 0; i < 4; i++)
#pragma unroll
    for (int j = 0; j < 4; j++)
#pragma unroll
      for (int r = 0; r < 4; r++) acc[i][j][r] = 0.f;

  STAGE_A(0, A, m0, 0)
  int p = 0;

  if (ysel < 2) {
    // ---- Q/K: swapped-operand K-loop; acc[j][i] = C^T tile ----
    for (int kt = 0; kt < DD; kt += 64) {
      __syncthreads();  // drains stage(kt); waves done reading buf p^1
      if (kt + 64 < DD) STAGE_A(p ^ 1, A, m0, kt + 64)
#pragma unroll
      for (int kk = 0; kk < 64; kk += 32) {
        LOAD_FRAGS_AB(p, kt, kk)
#pragma unroll
        for (int i = 0; i < 4; i++)
#pragma unroll
          for (int j = 0; j < 4; j++)
            acc[j][i] = __builtin_amdgcn_mfma_f32_16x16x32_bf16(
                bfr[j], af[i], acc[j][i], 0, 0, 0);
      }
      p ^= 1;
    }
    int cn = lane & 15;
    int quad = lane >> 4;
    float scale = (ysel == 0) ? 0.125f : 1.0f;  // fold 1/sqrt(64) into Q
    unsigned short* dst = (ysel == 0) ? qb : kb;
    int nb0 = n0 - ysel * 768;
#pragma unroll
    for (int j = 0; j < 4; j++)
#pragma unroll
      for (int i = 0; i < 4; i++) {
        int m = m0 + wm + i * 16 + cn;            // s dimension
        int nn = nb0 + wn + j * 16 + quad * 4;    // d dimension (4-consec)
        int b = m >> 12, s = m & 4095;
        int h = nn >> 6, d0 = nn & 63;
        uint2 pk;
        pk.x = (unsigned)f2bf(acc[j][i][0] * scale) |
               ((unsigned)f2bf(acc[j][i][1] * scale) << 16);
        pk.y = (unsigned)f2bf(acc[j][i][2] * scale) |
               ((unsigned)f2bf(acc[j][i][3] * scale) << 16);
        *(uint2*)&dst[(((size_t)b * HH + h) * SS + s) * HD + d0] = pk;
      }
  } else {
    // ---- V: normal K-loop; reg dim spans s (contig in [b][h][d][s]) ----
    for (int kt = 0; kt < DD; kt += 64) {
      __syncthreads();
      if (kt + 64 < DD) STAGE_A(p ^ 1, A, m0, kt + 64)
#pragma unroll
      for (int kk = 0; kk < 64; kk += 32) {
        LOAD_FRAGS_AB(p, kt, kk)
#pragma unroll
        for (int i = 0; i < 4; i++)
#pragma unroll
          for (int j = 0; j < 4; j++)
            acc[i][j] = __builtin_amdgcn_mfma_f32_16x16x32_bf16(
                af[i], bfr[j], acc[i][j], 0, 0, 0);
      }
      p ^= 1;
    }
    int cn = lane & 15;
    int quad = lane >> 4;
    int nb0 = n0 - 1536;
#pragma unroll
    for (int i = 0; i < 4; i++)
#pragma unroll
      for (int j = 0; j < 4; j++) {
        int m = m0 + wm + i * 16 + quad * 4;      // s base (4-consec)
        int nn = nb0 + wn + j * 16 + cn;          // d dimension
        int b = m >> 12, s0 = m & 4095;
        int h = nn >> 6, d = nn & 63;
        uint2 pk;
        pk.x = (unsigned)f2bf(acc[i][j][0]) |
               ((unsigned)f2bf(acc[i][j][1]) << 16);
        pk.y = (unsigned)f2bf(acc[i][j][2]) |
               ((unsigned)f2bf(acc[i][j][3]) << 16);
        *(uint2*)&vtb[(((size_t)b * HH + h) * HD + d) * SS + s0] = pk;
      }
  }
}

// ---------------------------------------------------------------------------
// Output projection, bf16 inputs, fp32 output (coalesced); A staged,
// B (Wo, 1.2 MB, L2-resident) direct from global.
// ---------------------------------------------------------------------------
__global__ __launch_bounds__(256, 4) void gemm_out_b(
    const unsigned short* __restrict__ A, const unsigned short* __restrict__ W,
    float* __restrict__ dst) {
  __shared__ unsigned short As[2][128 * 64];  // 32 KB
  int tid = threadIdx.x;
  int m0 = blockIdx.x * 128;
  int n0 = blockIdx.y * 128;
  int lane = tid & 63;
  int w = tid >> 6;
  int wm = (w >> 1) * 64;
  int wn = (w & 1) * 64;
  int fr = lane & 15;
  int qd = lane >> 4;
  const unsigned short* Wg = W + (size_t)(n0 + wn + fr) * DD + qd * 8;

  float4_t acc[4][4];
#pragma unroll
  for (int i = 0; i < 4; i++)
#pragma unroll
    for (int j = 0; j < 4; j++)
#pragma unroll
      for (int r = 0; r < 4; r++) acc[i][j][r] = 0.f;

  STAGE_A(0, A, m0, 0)
  int p = 0;
  for (int kt = 0; kt < DD; kt += 64) {
    __syncthreads();
    if (kt + 64 < DD) STAGE_A(p ^ 1, A, m0, kt + 64)
#pragma unroll
    for (int kk = 0; kk < 64; kk += 32) {
      LOAD_FRAGS_AB(p, kt, kk)
#pragma unroll
      for (int i = 0; i < 4; i++)
#pragma unroll
        for (int j = 0; j < 4; j++)
          acc[i][j] = __builtin_amdgcn_mfma_f32_16x16x32_bf16(
              af[i], bfr[j], acc[i][j], 0, 0, 0);
    }
    p ^= 1;
  }

  int cn = lane & 15;
  int rb = (lane >> 4) * 4;
#pragma unroll
  for (int i = 0; i < 4; i++)
#pragma unroll
    for (int j = 0; j < 4; j++)
#pragma unroll
      for (int r = 0; r < 4; r++) {
        int m = m0 + wm + i * 16 + rb + r;
        int n = n0 + wn + j * 16 + cn;
        dst[(size_t)m * DD + n] = acc[i][j][r];
      }
}

// ---------------------------------------------------------------------------
// Block-sparse attention, fixed-max softmax, dbuf K/V LDS, 1 barrier/iter.
// Heavy blocks (l=0,63) split 8 ways -> partial O + rowsum to scratch.
// Grid: ids 0..383 heavy chunks, 384..1871 lights.
// ---------------------------------------------------------------------------
__global__ __launch_bounds__(256) void attn2(
    const unsigned short* __restrict__ q, const unsigned short* __restrict__ k,
    const unsigned short* __restrict__ vt, const int* __restrict__ graph,
    unsigned short* __restrict__ ctxb, float* __restrict__ part) {
  __shared__ unsigned short Ks[2][64 * LDK];   // K[key][d]
  __shared__ unsigned short Vs[2][64 * LDK];   // V^T[d][key]
  __shared__ unsigned short Ps[4][16 * LDK];   // per-wave P[q][key]

  int tid = threadIdx.x;
  int id = blockIdx.x;
  int b, h, l, nkb, heavy, chunk = 0, hid = 0;
  int list[8];
  if (id < 384) {
    heavy = 1;
    hid = id >> 3;
    chunk = id & 7;
    b = hid / 24;
    int r = hid % 24;
    h = r >> 1;
    l = (r & 1) ? (NBK - 1) : 0;
    nkb = 8;
#pragma unroll
    for (int i = 0; i < 8; i++) list[i] = chunk * 8 + i;
  } else {
    heavy = 0;
    int j = id - 384;
    b = j / 744;  // 744 = 12*62
    int r = j % 744;
    h = r / 62;
    l = 1 + r % 62;
    const int* g = graph + (((size_t)b * HH + h) * NBK + l) * MC;
    int n = 0;
    if (l == 1) {
      list[0] = 0; list[1] = 1; list[2] = 2; list[3] = NBK - 1; n = 4;
    } else if (l == NBK - 2) {
      list[0] = 0; list[1] = NBK - 3; list[2] = NBK - 2; list[3] = NBK - 1; n = 4;
    } else {
      list[0] = 0; list[1] = l - 1; list[2] = l; list[3] = l + 1;
      list[4] = NBK - 1; n = 5;
    }
    for (int m = 0; m < MC; m++) list[n++] = g[m];
    nkb = n;
  }
  size_t base = ((size_t)b * HH + h) * SS * HD;

  int lane = tid & 63;
  int w = tid >> 6;
  int lr = lane & 15;     // fragment m/n index
  int quad = lane >> 4;   // fragment k-group

  // Q fragments (A-layout) straight from global into registers (q pre-scaled).
  short8_t qa[2];
  {
    const unsigned short* qp =
        q + base + (size_t)(l * 64 + w * 16 + lr) * HD + quad * 8;
    qa[0] = *(const short8_t*)qp;
    qa[1] = *(const short8_t*)(qp + 32);
  }

  float4_t Ot[4];
  float ls[4];  // per-lane partial row sums (4 cols/row this lane)
#pragma unroll
  for (int t = 0; t < 4; t++)
#pragma unroll
    for (int r = 0; r < 4; r++) Ot[t][r] = 0.f;
#pragma unroll
  for (int r = 0; r < 4; r++) ls[r] = 0.f;

  // staging: each thread moves 2x16B for K and 2x16B for Vt
  int srow = tid >> 3;          // 0..31
  int scol = (tid & 7) * 8;     // 0..56

  uint4 kr0, kr1, vr0, vr1;
  {
    int kb = list[0];
    const unsigned short* kp = k + base + (size_t)(kb * 64 + srow) * HD + scol;
    const unsigned short* vp = vt + base + (size_t)srow * SS + kb * 64 + scol;
    kr0 = *(const uint4*)kp;
    kr1 = *(const uint4*)(kp + 32 * HD);
    vr0 = *(const uint4*)vp;
    vr1 = *(const uint4*)(vp + 32 * SS);
  }
  // write block 0 into buf 0
  *(uint4*)&Ks[0][srow * LDK + scol] = kr0;
  *(uint4*)&Ks[0][(srow + 32) * LDK + scol] = kr1;
  *(uint4*)&Vs[0][srow * LDK + scol] = vr0;
  *(uint4*)&Vs[0][(srow + 32) * LDK + scol] = vr1;
  int p = 0;

  for (int t = 0; t < nkb; t++) {
    __syncthreads();  // buf[p] writes visible; all waves done reading buf[p^1]

    if (t + 1 < nkb) {  // issue next block's global loads (fly during compute)
      int kb = list[t + 1];
      const unsigned short* kp = k + base + (size_t)(kb * 64 + srow) * HD + scol;
      const unsigned short* vp = vt + base + (size_t)srow * SS + kb * 64 + scol;
      kr0 = *(const uint4*)kp;
      kr1 = *(const uint4*)(kp + 32 * HD);
      vr0 = *(const uint4*)vp;
      vr1 = *(const uint4*)(vp + 32 * SS);
    }

    // S = Q K^T
    float4_t st[4];
#pragma unroll
    for (int tt = 0; tt < 4; tt++) {
#pragma unroll
      for (int r = 0; r < 4; r++) st[tt][r] = 0.f;
      short8_t kb0 = *(const short8_t*)&Ks[p][(tt * 16 + lr) * LDK + quad * 8];
      short8_t kb1 =
          *(const short8_t*)&Ks[p][(tt * 16 + lr) * LDK + quad * 8 + 32];
      st[tt] = __builtin_amdgcn_mfma_f32_16x16x32_bf16(qa[0], kb0, st[tt], 0, 0, 0);
      st[tt] = __builtin_amdgcn_mfma_f32_16x16x32_bf16(qa[1], kb1, st[tt], 0, 0, 0);
    }

    // fixed-max softmax: p = exp(s); per-lane partial sums, no shuffles.
#pragma unroll
    for (int tt = 0; tt < 4; tt++)
#pragma unroll
      for (int r = 0; r < 4; r++) {
        float pv = __expf(st[tt][r]);
        st[tt][r] = pv;
        ls[r] += pv;
        Ps[w][(quad * 4 + r) * LDK + tt * 16 + lr] = f2bf(pv);
      }

    // O += P V
#pragma unroll
    for (int s = 0; s < 2; s++) {
      short8_t pa = *(const short8_t*)&Ps[w][lr * LDK + s * 32 + quad * 8];
#pragma unroll
      for (int tt = 0; tt < 4; tt++) {
        short8_t vb =
            *(const short8_t*)&Vs[p][(tt * 16 + lr) * LDK + s * 32 + quad * 8];
        Ot[tt] = __builtin_amdgcn_mfma_f32_16x16x32_bf16(pa, vb, Ot[tt], 0, 0, 0);
      }
    }

    if (t + 1 < nkb) {  // write prefetched regs into the other buffer
      *(uint4*)&Ks[p ^ 1][srow * LDK + scol] = kr0;
      *(uint4*)&Ks[p ^ 1][(srow + 32) * LDK + scol] = kr1;
      *(uint4*)&Vs[p ^ 1][srow * LDK + scol] = vr0;
      *(uint4*)&Vs[p ^ 1][(srow + 32) * LDK + scol] = vr1;
    }
    p ^= 1;
  }

  // reduce row sums across the 16 lanes holding each row
#pragma unroll
  for (int r = 0; r < 4; r++)
#pragma unroll
    for (int off = 1; off < 16; off <<= 1) ls[r] += __shfl_xor(ls[r], off);

  if (!heavy) {
#pragma unroll
    for (int r = 0; r < 4; r++) {
      float inv = 1.f / ls[r];
      size_t row = (size_t)b * SS + (size_t)l * 64 + w * 16 + quad * 4 + r;
#pragma unroll
      for (int tt = 0; tt < 4; tt++)
        ctxb[row * DD + h * HD + tt * 16 + lr] = f2bf(Ot[tt][r] * inv);
    }
  } else {
    float* pb = part + ((size_t)hid * 8 + chunk) * 4160;  // 64*64 O + 64 lsum
#pragma unroll
    for (int r = 0; r < 4; r++) {
      int rowi = w * 16 + quad * 4 + r;
#pragma unroll
      for (int tt = 0; tt < 4; tt++)
        pb[rowi * 64 + tt * 16 + lr] = Ot[tt][r];
      if (lr == 0) pb[4096 + rowi] = ls[r];
    }
  }
}

// ---------------------------------------------------------------------------
// Combine the 8 partials of each heavy block, normalize, write bf16 ctx.
// ---------------------------------------------------------------------------
__global__ __launch_bounds__(256) void reduce_heavy(
    const float* __restrict__ part, unsigned short* __restrict__ ctxb) {
  __shared__ float lrow[64];
  int hid = blockIdx.x;
  int tid = threadIdx.x;
  int b = hid / 24;
  int r = hid % 24;
  int h = r >> 1;
  int l = (r & 1) ? (NBK - 1) : 0;
  const float* pb = part + (size_t)hid * 8 * 4160;
  if (tid < 64) {
    float s = 0.f;
#pragma unroll
    for (int c = 0; c < 8; c++) s += pb[c * 4160 + 4096 + tid];
    lrow[tid] = s;
  }
  __syncthreads();
#pragma unroll
  for (int e = tid; e < 4096; e += 256) {
    float o = 0.f;
#pragma unroll
    for (int c = 0; c < 8; c++) o += pb[c * 4160 + e];
    int rowi = e >> 6, col = e & 63;
    size_t row = (size_t)b * SS + (size_t)l * 64 + rowi;
    ctxb[row * DD + h * HD + col] = f2bf(o / lrow[rowi]);
  }
}

extern "C" void kernel_launch(void* const* d_in, const int* in_sizes, int n_in,
                              void* d_out, int out_size, void* d_ws,
                              size_t ws_size, hipStream_t stream) {
  const float* hs = (const float*)d_in[0];
  const float* Wq = (const float*)d_in[1];
  const float* Wk = (const float*)d_in[2];
  const float* Wv = (const float*)d_in[3];
  const float* Wo = (const float*)d_in[4];
  const int* graph = (const int*)d_in[10];

  const size_t NHS = (size_t)BB * SS * DD;  // 6291456
  unsigned short* hsb = (unsigned short*)d_ws;
  unsigned short* wqkvb = hsb + NHS;            // 3*768*768
  unsigned short* wob = wqkvb + 3 * 768 * 768;  // 768*768
  unsigned short* qb = wob + 768 * 768;
  unsigned short* kb = qb + NHS;
  unsigned short* vtb = kb + NHS;
  unsigned short* ctxb = vtb + NHS;
  float* part = (float*)(ctxb + NHS);  // 48*8*4160 floats

  cvt_all<<<8448, 256, 0, stream>>>(hs, Wq, Wk, Wv, Wo, hsb, wqkvb, wob);
  gemm_qkv_b<<<dim3(64, 18, 1), 256, 0, stream>>>(hsb, wqkvb, qb, kb, vtb);
  attn2<<<1872, 256, 0, stream>>>(qb, kb, vtb, graph, ctxb, part);
  reduce_heavy<<<48, 256, 0, stream>>>(part, ctxb);
  gemm_out_b<<<dim3(64, 6, 1), 256, 0, stream>>>(ctxb, wob, (float*)d_out);
}

// Round 4
// 242.765 us; speedup vs baseline: 1.5865x; 1.0727x over previous
//
#include <hip/hip_runtime.h>
#include <hip/hip_bf16.h>

#define BB 2
#define HH 12
#define SS 4096
#define DD 768
#define HD 64
#define NBK 64
#define MC 3

typedef __attribute__((ext_vector_type(8))) short short8_t;
typedef __attribute__((ext_vector_type(4))) float float4_t;

__device__ __forceinline__ unsigned short f2bf(float f) {
  union { float f; unsigned u; } c;
  c.f = f;
  unsigned u = c.u + 0x7FFFu + ((c.u >> 16) & 1u);  // RNE
  return (unsigned short)(u >> 16);
}

// async 16B global -> LDS (gfx950). LDS dest = wave-uniform base + lane*16.
__device__ __forceinline__ void gload16(const unsigned short* gp,
                                        unsigned short* lp) {
  __builtin_amdgcn_global_load_lds(
      (const __attribute__((address_space(1))) unsigned int*)gp,
      (__attribute__((address_space(3))) unsigned int*)lp, 16, 0, 0);
}

#define LDK 72  // padded stride (attn kernel only)

// ---------------------------------------------------------------------------
// One-shot fp32 -> bf16 conversion: hs (8192x768), Wq|Wk|Wv packed (2304x768),
// Wo (768x768). One float4 per thread.
// ---------------------------------------------------------------------------
__global__ __launch_bounds__(256) void cvt_all(
    const float* __restrict__ hs, const float* __restrict__ Wq,
    const float* __restrict__ Wk, const float* __restrict__ Wv,
    const float* __restrict__ Wo, unsigned short* __restrict__ hsb,
    unsigned short* __restrict__ wqkvb, unsigned short* __restrict__ wob) {
  long i4 = (long)blockIdx.x * 256 + threadIdx.x;  // float4 index
  const float* src;
  unsigned short* dst;
  if (i4 < 1572864) {          // hs: 6291456 floats
    src = hs + i4 * 4;
    dst = hsb + i4 * 4;
  } else {
    long r = i4 - 1572864;
    int w = (int)(r / 147456);  // 0..3 : Wq,Wk,Wv,Wo (589824 floats each)
    long e = r % 147456;
    src = (w == 0 ? Wq : w == 1 ? Wk : w == 2 ? Wv : Wo) + e * 4;
    dst = (w < 3) ? (wqkvb + (long)w * 589824 + e * 4) : (wob + e * 4);
  }
  float4_t v = *(const float4_t*)src;
  uint2 p;
  p.x = (unsigned)f2bf(v[0]) | ((unsigned)f2bf(v[1]) << 16);
  p.y = (unsigned)f2bf(v[2]) | ((unsigned)f2bf(v[3]) << 16);
  *(uint2*)dst = p;
}

// ---------------------------------------------------------------------------
// GEMM helpers. A: double-buffered XOR-swizzled LDS (32 KB total). B
// (weights): NOT staged — panels are L2-resident (3.5 MB total, shared by
// 64 blocks each); fragments read directly from global per K-step, hidden
// under MFMA + cross-block TLP. Plain __launch_bounds__(256): NO min-wave
// hint (rounds 2/3 proved it clamps VGPR to 64/48 and spills the 64-reg
// accumulator to scratch). Single barrier per K-iter: A-prefetch of kt+64
// issues AFTER the barrier, flies during compute, drains at NEXT barrier.
// LDS row r = 64 shorts (8 chunks of 16B); global chunk c at slot c^(r&7).
// ---------------------------------------------------------------------------
#define STAGE_A(buf_, A_, m0_, kt_)                                           \
  {                                                                           \
    int rr_ = lane >> 3;                                                      \
    int cg_ = (lane & 7) ^ rr_;                                               \
    _Pragma("unroll") for (int u = 0; u < 4; u++) {                           \
      int g_ = w * 4 + u;                                                     \
      gload16(A_ + (size_t)(m0_ + g_ * 8 + rr_) * DD + kt_ + cg_ * 8,         \
              &As[buf_][g_ * 512]);                                           \
    }                                                                         \
  }

#define LOAD_FRAGS_AB(buf_, kt_, kk_)                                         \
  int cb = qd + ((kk_) >> 3);                                                 \
  short8_t af[4], bfr[4];                                                     \
  _Pragma("unroll") for (int i = 0; i < 4; i++) {                             \
    int r_ = wm + i * 16 + fr;                                                \
    af[i] = *(const short8_t*)&As[buf_][r_ * 64 + (cb ^ (fr & 7)) * 8];       \
  }                                                                           \
  _Pragma("unroll") for (int j = 0; j < 4; j++)                               \
    bfr[j] = *(const short8_t*)&Wg[(size_t)(j * 16) * DD + (kt_) + (kk_)];

// ---------------------------------------------------------------------------
// QKV projection, bf16 inputs, A staged via gload_lds, B direct from L2.
// Q/K tiles: SWAPPED operands (C^T, reg dim spans d) -> packed uint2 stores.
// V: normal orientation (reg dim spans s) -> packed uint2 stores transposed.
// ---------------------------------------------------------------------------
__global__ __launch_bounds__(256) void gemm_qkv_b(
    const unsigned short* __restrict__ A, const unsigned short* __restrict__ W,
    unsigned short* __restrict__ qb, unsigned short* __restrict__ kb,
    unsigned short* __restrict__ vtb) {
  __shared__ unsigned short As[2][128 * 64];  // 32 KB
  int tid = threadIdx.x;
  int m0 = blockIdx.x * 128;
  int n0 = blockIdx.y * 128;  // 0..2176, never straddles a 768 boundary
  int lane = tid & 63;
  int w = tid >> 6;
  int wm = (w >> 1) * 64;
  int wn = (w & 1) * 64;
  int fr = lane & 15;
  int qd = lane >> 4;
  int ysel = n0 / 768;
  // per-lane base into the B (weights) panel: row n0+wn+fr, col qd*8
  const unsigned short* Wg = W + (size_t)(n0 + wn + fr) * DD + qd * 8;

  float4_t acc[4][4];
#pragma unroll
  for (int i = 0; i < 4; i++)
#pragma unroll
    for (int j = 0; j < 4; j++)
#pragma unroll
      for (int r = 0; r < 4; r++) acc[i][j][r] = 0.f;

  STAGE_A(0, A, m0, 0)
  int p = 0;

  if (ysel < 2) {
    // ---- Q/K: swapped-operand K-loop; acc[j][i] = C^T tile ----
    for (int kt = 0; kt < DD; kt += 64) {
      __syncthreads();  // drains stage(kt); waves done reading buf p^1
      if (kt + 64 < DD) STAGE_A(p ^ 1, A, m0, kt + 64)
#pragma unroll
      for (int kk = 0; kk < 64; kk += 32) {
        LOAD_FRAGS_AB(p, kt, kk)
#pragma unroll
        for (int i = 0; i < 4; i++)
#pragma unroll
          for (int j = 0; j < 4; j++)
            acc[j][i] = __builtin_amdgcn_mfma_f32_16x16x32_bf16(
                bfr[j], af[i], acc[j][i], 0, 0, 0);
      }
      p ^= 1;
    }
    int cn = lane & 15;
    int quad = lane >> 4;
    float scale = (ysel == 0) ? 0.125f : 1.0f;  // fold 1/sqrt(64) into Q
    unsigned short* dst = (ysel == 0) ? qb : kb;
    int nb0 = n0 - ysel * 768;
#pragma unroll
    for (int j = 0; j < 4; j++)
#pragma unroll
      for (int i = 0; i < 4; i++) {
        int m = m0 + wm + i * 16 + cn;            // s dimension
        int nn = nb0 + wn + j * 16 + quad * 4;    // d dimension (4-consec)
        int b = m >> 12, s = m & 4095;
        int h = nn >> 6, d0 = nn & 63;
        uint2 pk;
        pk.x = (unsigned)f2bf(acc[j][i][0] * scale) |
               ((unsigned)f2bf(acc[j][i][1] * scale) << 16);
        pk.y = (unsigned)f2bf(acc[j][i][2] * scale) |
               ((unsigned)f2bf(acc[j][i][3] * scale) << 16);
        *(uint2*)&dst[(((size_t)b * HH + h) * SS + s) * HD + d0] = pk;
      }
  } else {
    // ---- V: normal K-loop; reg dim spans s (contig in [b][h][d][s]) ----
    for (int kt = 0; kt < DD; kt += 64) {
      __syncthreads();
      if (kt + 64 < DD) STAGE_A(p ^ 1, A, m0, kt + 64)
#pragma unroll
      for (int kk = 0; kk < 64; kk += 32) {
        LOAD_FRAGS_AB(p, kt, kk)
#pragma unroll
        for (int i = 0; i < 4; i++)
#pragma unroll
          for (int j = 0; j < 4; j++)
            acc[i][j] = __builtin_amdgcn_mfma_f32_16x16x32_bf16(
                af[i], bfr[j], acc[i][j], 0, 0, 0);
      }
      p ^= 1;
    }
    int cn = lane & 15;
    int quad = lane >> 4;
    int nb0 = n0 - 1536;
#pragma unroll
    for (int i = 0; i < 4; i++)
#pragma unroll
      for (int j = 0; j < 4; j++) {
        int m = m0 + wm + i * 16 + quad * 4;      // s base (4-consec)
        int nn = nb0 + wn + j * 16 + cn;          // d dimension
        int b = m >> 12, s0 = m & 4095;
        int h = nn >> 6, d = nn & 63;
        uint2 pk;
        pk.x = (unsigned)f2bf(acc[i][j][0]) |
               ((unsigned)f2bf(acc[i][j][1]) << 16);
        pk.y = (unsigned)f2bf(acc[i][j][2]) |
               ((unsigned)f2bf(acc[i][j][3]) << 16);
        *(uint2*)&vtb[(((size_t)b * HH + h) * HD + d) * SS + s0] = pk;
      }
  }
}

// ---------------------------------------------------------------------------
// Output projection, bf16 inputs, fp32 output (coalesced); A staged,
// B (Wo, 1.2 MB, L2-resident) direct from global.
// ---------------------------------------------------------------------------
__global__ __launch_bounds__(256) void gemm_out_b(
    const unsigned short* __restrict__ A, const unsigned short* __restrict__ W,
    float* __restrict__ dst) {
  __shared__ unsigned short As[2][128 * 64];  // 32 KB
  int tid = threadIdx.x;
  int m0 = blockIdx.x * 128;
  int n0 = blockIdx.y * 128;
  int lane = tid & 63;
  int w = tid >> 6;
  int wm = (w >> 1) * 64;
  int wn = (w & 1) * 64;
  int fr = lane & 15;
  int qd = lane >> 4;
  const unsigned short* Wg = W + (size_t)(n0 + wn + fr) * DD + qd * 8;

  float4_t acc[4][4];
#pragma unroll
  for (int i = 0; i < 4; i++)
#pragma unroll
    for (int j = 0; j < 4; j++)
#pragma unroll
      for (int r = 0; r < 4; r++) acc[i][j][r] = 0.f;

  STAGE_A(0, A, m0, 0)
  int p = 0;
  for (int kt = 0; kt < DD; kt += 64) {
    __syncthreads();
    if (kt + 64 < DD) STAGE_A(p ^ 1, A, m0, kt + 64)
#pragma unroll
    for (int kk = 0; kk < 64; kk += 32) {
      LOAD_FRAGS_AB(p, kt, kk)
#pragma unroll
      for (int i = 0; i < 4; i++)
#pragma unroll
        for (int j = 0; j < 4; j++)
          acc[i][j] = __builtin_amdgcn_mfma_f32_16x16x32_bf16(
              af[i], bfr[j], acc[i][j], 0, 0, 0);
    }
    p ^= 1;
  }

  int cn = lane & 15;
  int rb = (lane >> 4) * 4;
#pragma unroll
  for (int i = 0; i < 4; i++)
#pragma unroll
    for (int j = 0; j < 4; j++)
#pragma unroll
      for (int r = 0; r < 4; r++) {
        int m = m0 + wm + i * 16 + rb + r;
        int n = n0 + wn + j * 16 + cn;
        dst[(size_t)m * DD + n] = acc[i][j][r];
      }
}

// ---------------------------------------------------------------------------
// Block-sparse attention, fixed-max softmax, dbuf K/V LDS, 1 barrier/iter.
// Heavy blocks (l=0,63) split 8 ways -> partial O + rowsum to scratch.
// Grid: ids 0..383 heavy chunks, 384..1871 lights.
// ---------------------------------------------------------------------------
__global__ __launch_bounds__(256) void attn2(
    const unsigned short* __restrict__ q, const unsigned short* __restrict__ k,
    const unsigned short* __restrict__ vt, const int* __restrict__ graph,
    unsigned short* __restrict__ ctxb, float* __restrict__ part) {
  __shared__ unsigned short Ks[2][64 * LDK];   // K[key][d]
  __shared__ unsigned short Vs[2][64 * LDK];   // V^T[d][key]
  __shared__ unsigned short Ps[4][16 * LDK];   // per-wave P[q][key]

  int tid = threadIdx.x;
  int id = blockIdx.x;
  int b, h, l, nkb, heavy, chunk = 0, hid = 0;
  int list[8];
  if (id < 384) {
    heavy = 1;
    hid = id >> 3;
    chunk = id & 7;
    b = hid / 24;
    int r = hid % 24;
    h = r >> 1;
    l = (r & 1) ? (NBK - 1) : 0;
    nkb = 8;
#pragma unroll
    for (int i = 0; i < 8; i++) list[i] = chunk * 8 + i;
  } else {
    heavy = 0;
    int j = id - 384;
    b = j / 744;  // 744 = 12*62
    int r = j % 744;
    h = r / 62;
    l = 1 + r % 62;
    const int* g = graph + (((size_t)b * HH + h) * NBK + l) * MC;
    int n = 0;
    if (l == 1) {
      list[0] = 0; list[1] = 1; list[2] = 2; list[3] = NBK - 1; n = 4;
    } else if (l == NBK - 2) {
      list[0] = 0; list[1] = NBK - 3; list[2] = NBK - 2; list[3] = NBK - 1; n = 4;
    } else {
      list[0] = 0; list[1] = l - 1; list[2] = l; list[3] = l + 1;
      list[4] = NBK - 1; n = 5;
    }
    for (int m = 0; m < MC; m++) list[n++] = g[m];
    nkb = n;
  }
  size_t base = ((size_t)b * HH + h) * SS * HD;

  int lane = tid & 63;
  int w = tid >> 6;
  int lr = lane & 15;     // fragment m/n index
  int quad = lane >> 4;   // fragment k-group

  // Q fragments (A-layout) straight from global into registers (q pre-scaled).
  short8_t qa[2];
  {
    const unsigned short* qp =
        q + base + (size_t)(l * 64 + w * 16 + lr) * HD + quad * 8;
    qa[0] = *(const short8_t*)qp;
    qa[1] = *(const short8_t*)(qp + 32);
  }

  float4_t Ot[4];
  float ls[4];  // per-lane partial row sums (4 cols/row this lane)
#pragma unroll
  for (int t = 0; t < 4; t++)
#pragma unroll
    for (int r = 0; r < 4; r++) Ot[t][r] = 0.f;
#pragma unroll
  for (int r = 0; r < 4; r++) ls[r] = 0.f;

  // staging: each thread moves 2x16B for K and 2x16B for Vt
  int srow = tid >> 3;          // 0..31
  int scol = (tid & 7) * 8;     // 0..56

  uint4 kr0, kr1, vr0, vr1;
  {
    int kb = list[0];
    const unsigned short* kp = k + base + (size_t)(kb * 64 + srow) * HD + scol;
    const unsigned short* vp = vt + base + (size_t)srow * SS + kb * 64 + scol;
    kr0 = *(const uint4*)kp;
    kr1 = *(const uint4*)(kp + 32 * HD);
    vr0 = *(const uint4*)vp;
    vr1 = *(const uint4*)(vp + 32 * SS);
  }
  // write block 0 into buf 0
  *(uint4*)&Ks[0][srow * LDK + scol] = kr0;
  *(uint4*)&Ks[0][(srow + 32) * LDK + scol] = kr1;
  *(uint4*)&Vs[0][srow * LDK + scol] = vr0;
  *(uint4*)&Vs[0][(srow + 32) * LDK + scol] = vr1;
  int p = 0;

  for (int t = 0; t < nkb; t++) {
    __syncthreads();  // buf[p] writes visible; all waves done reading buf[p^1]

    if (t + 1 < nkb) {  // issue next block's global loads (fly during compute)
      int kb = list[t + 1];
      const unsigned short* kp = k + base + (size_t)(kb * 64 + srow) * HD + scol;
      const unsigned short* vp = vt + base + (size_t)srow * SS + kb * 64 + scol;
      kr0 = *(const uint4*)kp;
      kr1 = *(const uint4*)(kp + 32 * HD);
      vr0 = *(const uint4*)vp;
      vr1 = *(const uint4*)(vp + 32 * SS);
    }

    // S = Q K^T
    float4_t st[4];
#pragma unroll
    for (int tt = 0; tt < 4; tt++) {
#pragma unroll
      for (int r = 0; r < 4; r++) st[tt][r] = 0.f;
      short8_t kb0 = *(const short8_t*)&Ks[p][(tt * 16 + lr) * LDK + quad * 8];
      short8_t kb1 =
          *(const short8_t*)&Ks[p][(tt * 16 + lr) * LDK + quad * 8 + 32];
      st[tt] = __builtin_amdgcn_mfma_f32_16x16x32_bf16(qa[0], kb0, st[tt], 0, 0, 0);
      st[tt] = __builtin_amdgcn_mfma_f32_16x16x32_bf16(qa[1], kb1, st[tt], 0, 0, 0);
    }

    // fixed-max softmax: p = exp(s); per-lane partial sums, no shuffles.
#pragma unroll
    for (int tt = 0; tt < 4; tt++)
#pragma unroll
      for (int r = 0; r < 4; r++) {
        float pv = __expf(st[tt][r]);
        st[tt][r] = pv;
        ls[r] += pv;
        Ps[w][(quad * 4 + r) * LDK + tt * 16 + lr] = f2bf(pv);
      }

    // O += P V
#pragma unroll
    for (int s = 0; s < 2; s++) {
      short8_t pa = *(const short8_t*)&Ps[w][lr * LDK + s * 32 + quad * 8];
#pragma unroll
      for (int tt = 0; tt < 4; tt++) {
        short8_t vb =
            *(const short8_t*)&Vs[p][(tt * 16 + lr) * LDK + s * 32 + quad * 8];
        Ot[tt] = __builtin_amdgcn_mfma_f32_16x16x32_bf16(pa, vb, Ot[tt], 0, 0, 0);
      }
    }

    if (t + 1 < nkb) {  // write prefetched regs into the other buffer
      *(uint4*)&Ks[p ^ 1][srow * LDK + scol] = kr0;
      *(uint4*)&Ks[p ^ 1][(srow + 32) * LDK + scol] = kr1;
      *(uint4*)&Vs[p ^ 1][srow * LDK + scol] = vr0;
      *(uint4*)&Vs[p ^ 1][(srow + 32) * LDK + scol] = vr1;
    }
    p ^= 1;
  }

  // reduce row sums across the 16 lanes holding each row
#pragma unroll
  for (int r = 0; r < 4; r++)
#pragma unroll
    for (int off = 1; off < 16; off <<= 1) ls[r] += __shfl_xor(ls[r], off);

  if (!heavy) {
#pragma unroll
    for (int r = 0; r < 4; r++) {
      float inv = 1.f / ls[r];
      size_t row = (size_t)b * SS + (size_t)l * 64 + w * 16 + quad * 4 + r;
#pragma unroll
      for (int tt = 0; tt < 4; tt++)
        ctxb[row * DD + h * HD + tt * 16 + lr] = f2bf(Ot[tt][r] * inv);
    }
  } else {
    float* pb = part + ((size_t)hid * 8 + chunk) * 4160;  // 64*64 O + 64 lsum
#pragma unroll
    for (int r = 0; r < 4; r++) {
      int rowi = w * 16 + quad * 4 + r;
#pragma unroll
      for (int tt = 0; tt < 4; tt++)
        pb[rowi * 64 + tt * 16 + lr] = Ot[tt][r];
      if (lr == 0) pb[4096 + rowi] = ls[r];
    }
  }
}

// ---------------------------------------------------------------------------
// Combine the 8 partials of each heavy block, normalize, write bf16 ctx.
// ---------------------------------------------------------------------------
__global__ __launch_bounds__(256) void reduce_heavy(
    const float* __restrict__ part, unsigned short* __restrict__ ctxb) {
  __shared__ float lrow[64];
  int hid = blockIdx.x;
  int tid = threadIdx.x;
  int b = hid / 24;
  int r = hid % 24;
  int h = r >> 1;
  int l = (r & 1) ? (NBK - 1) : 0;
  const float* pb = part + (size_t)hid * 8 * 4160;
  if (tid < 64) {
    float s = 0.f;
#pragma unroll
    for (int c = 0; c < 8; c++) s += pb[c * 4160 + 4096 + tid];
    lrow[tid] = s;
  }
  __syncthreads();
#pragma unroll
  for (int e = tid; e < 4096; e += 256) {
    float o = 0.f;
#pragma unroll
    for (int c = 0; c < 8; c++) o += pb[c * 4160 + e];
    int rowi = e >> 6, col = e & 63;
    size_t row = (size_t)b * SS + (size_t)l * 64 + rowi;
    ctxb[row * DD + h * HD + col] = f2bf(o / lrow[rowi]);
  }
}

extern "C" void kernel_launch(void* const* d_in, const int* in_sizes, int n_in,
                              void* d_out, int out_size, void* d_ws,
                              size_t ws_size, hipStream_t stream) {
  const float* hs = (const float*)d_in[0];
  const float* Wq = (const float*)d_in[1];
  const float* Wk = (const float*)d_in[2];
  const float* Wv = (const float*)d_in[3];
  const float* Wo = (const float*)d_in[4];
  const int* graph = (const int*)d_in[10];

  const size_t NHS = (size_t)BB * SS * DD;  // 6291456
  unsigned short* hsb = (unsigned short*)d_ws;
  unsigned short* wqkvb = hsb + NHS;            // 3*768*768
  unsigned short* wob = wqkvb + 3 * 768 * 768;  // 768*768
  unsigned short* qb = wob + 768 * 768;
  unsigned short* kb = qb + NHS;
  unsigned short* vtb = kb + NHS;
  unsigned short* ctxb = vtb + NHS;
  float* part = (float*)(ctxb + NHS);  // 48*8*4160 floats

  cvt_all<<<8448, 256, 0, stream>>>(hs, Wq, Wk, Wv, Wo, hsb, wqkvb, wob);
  gemm_qkv_b<<<dim3(64, 18, 1), 256, 0, stream>>>(hsb, wqkvb, qb, kb, vtb);
  attn2<<<1872, 256, 0, stream>>>(qb, kb, vtb, graph, ctxb, part);
  reduce_heavy<<<48, 256, 0, stream>>>(part, ctxb);
  gemm_out_b<<<dim3(64, 6, 1), 256, 0, stream>>>(ctxb, wob, (float*)d_out);
}

// Round 5
// 218.970 us; speedup vs baseline: 1.7589x; 1.1087x over previous
//
#include <hip/hip_runtime.h>
#include <hip/hip_bf16.h>

#define BB 2
#define HH 12
#define SS 4096
#define DD 768
#define HD 64
#define NBK 64
#define MC 3

typedef __attribute__((ext_vector_type(8))) short short8_t;
typedef __attribute__((ext_vector_type(4))) float float4_t;

__device__ __forceinline__ unsigned short f2bf(float f) {
  union { float f; unsigned u; } c;
  c.f = f;
  unsigned u = c.u + 0x7FFFu + ((c.u >> 16) & 1u);  // RNE
  return (unsigned short)(u >> 16);
}

// async 16B global -> LDS (gfx950). LDS dest = wave-uniform base + lane*16.
__device__ __forceinline__ void gload16(const unsigned short* gp,
                                        unsigned short* lp) {
  __builtin_amdgcn_global_load_lds(
      (const __attribute__((address_space(1))) unsigned int*)gp,
      (__attribute__((address_space(3))) unsigned int*)lp, 16, 0, 0);
}

#define LDK 72  // padded stride (attn kernel only)

// ---------------------------------------------------------------------------
// One-shot fp32 -> bf16 conversion: hs (8192x768), Wq|Wk|Wv packed (2304x768),
// Wo (768x768). One float4 per thread.
// ---------------------------------------------------------------------------
__global__ __launch_bounds__(256) void cvt_all(
    const float* __restrict__ hs, const float* __restrict__ Wq,
    const float* __restrict__ Wk, const float* __restrict__ Wv,
    const float* __restrict__ Wo, unsigned short* __restrict__ hsb,
    unsigned short* __restrict__ wqkvb, unsigned short* __restrict__ wob) {
  long i4 = (long)blockIdx.x * 256 + threadIdx.x;  // float4 index
  const float* src;
  unsigned short* dst;
  if (i4 < 1572864) {          // hs: 6291456 floats
    src = hs + i4 * 4;
    dst = hsb + i4 * 4;
  } else {
    long r = i4 - 1572864;
    int w = (int)(r / 147456);  // 0..3 : Wq,Wk,Wv,Wo (589824 floats each)
    long e = r % 147456;
    src = (w == 0 ? Wq : w == 1 ? Wk : w == 2 ? Wv : Wo) + e * 4;
    dst = (w < 3) ? (wqkvb + (long)w * 589824 + e * 4) : (wob + e * 4);
  }
  float4_t v = *(const float4_t*)src;
  uint2 p;
  p.x = (unsigned)f2bf(v[0]) | ((unsigned)f2bf(v[1]) << 16);
  p.y = (unsigned)f2bf(v[2]) | ((unsigned)f2bf(v[3]) << 16);
  *(uint2*)dst = p;
}

// ---------------------------------------------------------------------------
// GEMM, BK=32, 3-slot LDS rotation (48 KB -> 3 blocks/CU), counted-vmcnt
// boundaries. Prefetch distance = 2 compute phases (~2x450 cyc) covers HBM
// latency (~900 cyc); boundary wait is vmcnt(4) (next tile's 4 loads stay
// in flight), never a drain except the last iter. Raw s_barrier with
// explicit "vmcnt(N) lgkmcnt(0)" (lgkmcnt(0) keeps ds_reads ordered before
// barrier passage; __syncthreads would force vmcnt(0) and kill the
// pipeline). NO min-waves hint in __launch_bounds__ (rounds 2/3: it clamps
// VGPR below the 64-reg accumulator and spills to scratch).
//
// LDS row = 32 shorts = 64 B = 4 chunks of 16B. Swizzle: global chunk c of
// row r sits in slot c ^ (r&3) ^ ((r>>2)&3). For the fragment read
// (16 rows x 4 quads per wave, ds_read_b128) this spreads the 64 lanes
// evenly over all 8 bank-quads: exactly 2 lanes/bank = free (m136).
// Race-freedom: stage(T+2) targets slot (T+2)%3 == (T-1)%3, whose readers
// finished before the barrier at top of iter T; gload_lds issues after it.
// ---------------------------------------------------------------------------
#define BOUND4()                                                           \
  do {                                                                     \
    asm volatile("s_waitcnt vmcnt(4) lgkmcnt(0)" ::: "memory");            \
    __builtin_amdgcn_s_barrier();                                          \
    asm volatile("" ::: "memory");                                         \
  } while (0)
#define BOUND0()                                                           \
  do {                                                                     \
    asm volatile("s_waitcnt vmcnt(0) lgkmcnt(0)" ::: "memory");            \
    __builtin_amdgcn_s_barrier();                                          \
    asm volatile("" ::: "memory");                                         \
  } while (0)

// one stage = 4 gload16/thread (A rows 0-63 & 64-127, B same), 8 KB each op
#define STAGE3(s_, kt_)                                                    \
  {                                                                        \
    gload16(Ag + (kt_), &As[s_][wbase]);                                   \
    gload16(Ag + (kt_) + 64 * DD, &As[s_][wbase + 2048]);                  \
    gload16(Bg + (kt_), &Bs[s_][wbase]);                                   \
    gload16(Bg + (kt_) + 64 * DD, &Bs[s_][wbase + 2048]);                  \
  }

// full K loop: 24 iters, MM(i,j) is the accumulate statement
#define KLOOP3(MM)                                                         \
  STAGE3(0, 0)                                                             \
  STAGE3(1, 32)                                                            \
  int sl = 0;                                                              \
  for (int T = 0; T < 24; T++) {                                           \
    if (T == 23) { BOUND0(); } else { BOUND4(); }                          \
    if (T + 2 < 24) {                                                      \
      int s2 = sl + 2;                                                     \
      if (s2 >= 3) s2 -= 3;                                                \
      STAGE3(s2, (T + 2) * 32)                                             \
    }                                                                      \
    short8_t af[4], bfr[4];                                                \
    _Pragma("unroll") for (int i = 0; i < 4; i++)                          \
        af[i] = *(const short8_t*)&As[sl][(wm + i * 16 + fr) * 32 +        \
                                          fslot * 8];                      \
    _Pragma("unroll") for (int j = 0; j < 4; j++)                          \
        bfr[j] = *(const short8_t*)&Bs[sl][(wn + j * 16 + fr) * 32 +       \
                                           fslot * 8];                     \
    _Pragma("unroll") for (int i = 0; i < 4; i++)                          \
        _Pragma("unroll") for (int j = 0; j < 4; j++) { MM(i, j) }         \
    sl = (sl == 2) ? 0 : sl + 1;                                           \
  }

#define MMQK(i, j)                                                         \
  acc[j][i] = __builtin_amdgcn_mfma_f32_16x16x32_bf16(bfr[j], af[i],       \
                                                      acc[j][i], 0, 0, 0);
#define MMN(i, j)                                                          \
  acc[i][j] = __builtin_amdgcn_mfma_f32_16x16x32_bf16(af[i], bfr[j],       \
                                                      acc[i][j], 0, 0, 0);

// ---------------------------------------------------------------------------
// QKV projection, bf16 inputs. Q/K: SWAPPED operands (C^T, reg dim spans d)
// -> packed uint2 stores. V: normal (reg dim spans s) -> stores transposed.
// ---------------------------------------------------------------------------
__global__ __launch_bounds__(256) void gemm_qkv_b(
    const unsigned short* __restrict__ A, const unsigned short* __restrict__ W,
    unsigned short* __restrict__ qb, unsigned short* __restrict__ kb,
    unsigned short* __restrict__ vtb) {
  __shared__ unsigned short As[3][128 * 32];  // 24 KB
  __shared__ unsigned short Bs[3][128 * 32];  // 24 KB
  int tid = threadIdx.x;
  int m0 = blockIdx.x * 128;
  int n0 = blockIdx.y * 128;  // 0..2176, never straddles a 768 boundary
  int lane = tid & 63;
  int w = tid >> 6;
  int wm = (w >> 1) * 64;
  int wn = (w & 1) * 64;
  int fr = lane & 15;
  int qd = lane >> 4;
  int fslot = qd ^ (fr & 3) ^ ((fr >> 2) & 3);  // swizzled read chunk
  // staging: lane -> row lane>>2 (within 16-row wave strip), chunk lane&3
  int srow = w * 16 + (lane >> 2);
  int scg = (lane & 3) ^ ((lane >> 2) & 3) ^ ((lane >> 4) & 3);
  int wbase = w * 512;  // wave-uniform LDS base (shorts)
  const unsigned short* Ag = A + (size_t)(m0 + srow) * DD + scg * 8;
  const unsigned short* Bg = W + (size_t)(n0 + srow) * DD + scg * 8;
  int ysel = n0 / 768;

  float4_t acc[4][4];
#pragma unroll
  for (int i = 0; i < 4; i++)
#pragma unroll
    for (int j = 0; j < 4; j++)
#pragma unroll
      for (int r = 0; r < 4; r++) acc[i][j][r] = 0.f;

  if (ysel < 2) {
    KLOOP3(MMQK)
    int cn = lane & 15;
    int quad = lane >> 4;
    float scale = (ysel == 0) ? 0.125f : 1.0f;  // fold 1/sqrt(64) into Q
    unsigned short* dst = (ysel == 0) ? qb : kb;
    int nb0 = n0 - ysel * 768;
#pragma unroll
    for (int j = 0; j < 4; j++)
#pragma unroll
      for (int i = 0; i < 4; i++) {
        int m = m0 + wm + i * 16 + cn;            // s dimension
        int nn = nb0 + wn + j * 16 + quad * 4;    // d dimension (4-consec)
        int b = m >> 12, s = m & 4095;
        int h = nn >> 6, d0 = nn & 63;
        uint2 pk;
        pk.x = (unsigned)f2bf(acc[j][i][0] * scale) |
               ((unsigned)f2bf(acc[j][i][1] * scale) << 16);
        pk.y = (unsigned)f2bf(acc[j][i][2] * scale) |
               ((unsigned)f2bf(acc[j][i][3] * scale) << 16);
        *(uint2*)&dst[(((size_t)b * HH + h) * SS + s) * HD + d0] = pk;
      }
  } else {
    KLOOP3(MMN)
    int cn = lane & 15;
    int quad = lane >> 4;
    int nb0 = n0 - 1536;
#pragma unroll
    for (int i = 0; i < 4; i++)
#pragma unroll
      for (int j = 0; j < 4; j++) {
        int m = m0 + wm + i * 16 + quad * 4;      // s base (4-consec)
        int nn = nb0 + wn + j * 16 + cn;          // d dimension
        int b = m >> 12, s0 = m & 4095;
        int h = nn >> 6, d = nn & 63;
        uint2 pk;
        pk.x = (unsigned)f2bf(acc[i][j][0]) |
               ((unsigned)f2bf(acc[i][j][1]) << 16);
        pk.y = (unsigned)f2bf(acc[i][j][2]) |
               ((unsigned)f2bf(acc[i][j][3]) << 16);
        *(uint2*)&vtb[(((size_t)b * HH + h) * HD + d) * SS + s0] = pk;
      }
  }
}

// ---------------------------------------------------------------------------
// Output projection, bf16 inputs, fp32 output (coalesced), same pipeline.
// ---------------------------------------------------------------------------
__global__ __launch_bounds__(256) void gemm_out_b(
    const unsigned short* __restrict__ A, const unsigned short* __restrict__ W,
    float* __restrict__ dst) {
  __shared__ unsigned short As[3][128 * 32];
  __shared__ unsigned short Bs[3][128 * 32];
  int tid = threadIdx.x;
  int m0 = blockIdx.x * 128;
  int n0 = blockIdx.y * 128;
  int lane = tid & 63;
  int w = tid >> 6;
  int wm = (w >> 1) * 64;
  int wn = (w & 1) * 64;
  int fr = lane & 15;
  int qd = lane >> 4;
  int fslot = qd ^ (fr & 3) ^ ((fr >> 2) & 3);
  int srow = w * 16 + (lane >> 2);
  int scg = (lane & 3) ^ ((lane >> 2) & 3) ^ ((lane >> 4) & 3);
  int wbase = w * 512;
  const unsigned short* Ag = A + (size_t)(m0 + srow) * DD + scg * 8;
  const unsigned short* Bg = W + (size_t)(n0 + srow) * DD + scg * 8;

  float4_t acc[4][4];
#pragma unroll
  for (int i = 0; i < 4; i++)
#pragma unroll
    for (int j = 0; j < 4; j++)
#pragma unroll
      for (int r = 0; r < 4; r++) acc[i][j][r] = 0.f;

  KLOOP3(MMN)

  int cn = lane & 15;
  int rb = (lane >> 4) * 4;
#pragma unroll
  for (int i = 0; i < 4; i++)
#pragma unroll
    for (int j = 0; j < 4; j++)
#pragma unroll
      for (int r = 0; r < 4; r++) {
        int m = m0 + wm + i * 16 + rb + r;
        int n = n0 + wn + j * 16 + cn;
        dst[(size_t)m * DD + n] = acc[i][j][r];
      }
}

// ---------------------------------------------------------------------------
// Block-sparse attention, fixed-max softmax, dbuf K/V LDS, 1 barrier/iter.
// Heavy blocks (l=0,63) split 8 ways -> partial O + rowsum to scratch.
// Grid: ids 0..383 heavy chunks, 384..1871 lights.
// ---------------------------------------------------------------------------
__global__ __launch_bounds__(256) void attn2(
    const unsigned short* __restrict__ q, const unsigned short* __restrict__ k,
    const unsigned short* __restrict__ vt, const int* __restrict__ graph,
    unsigned short* __restrict__ ctxb, float* __restrict__ part) {
  __shared__ unsigned short Ks[2][64 * LDK];   // K[key][d]
  __shared__ unsigned short Vs[2][64 * LDK];   // V^T[d][key]
  __shared__ unsigned short Ps[4][16 * LDK];   // per-wave P[q][key]

  int tid = threadIdx.x;
  int id = blockIdx.x;
  int b, h, l, nkb, heavy, chunk = 0, hid = 0;
  int list[8];
  if (id < 384) {
    heavy = 1;
    hid = id >> 3;
    chunk = id & 7;
    b = hid / 24;
    int r = hid % 24;
    h = r >> 1;
    l = (r & 1) ? (NBK - 1) : 0;
    nkb = 8;
#pragma unroll
    for (int i = 0; i < 8; i++) list[i] = chunk * 8 + i;
  } else {
    heavy = 0;
    int j = id - 384;
    b = j / 744;  // 744 = 12*62
    int r = j % 744;
    h = r / 62;
    l = 1 + r % 62;
    const int* g = graph + (((size_t)b * HH + h) * NBK + l) * MC;
    int n = 0;
    if (l == 1) {
      list[0] = 0; list[1] = 1; list[2] = 2; list[3] = NBK - 1; n = 4;
    } else if (l == NBK - 2) {
      list[0] = 0; list[1] = NBK - 3; list[2] = NBK - 2; list[3] = NBK - 1; n = 4;
    } else {
      list[0] = 0; list[1] = l - 1; list[2] = l; list[3] = l + 1;
      list[4] = NBK - 1; n = 5;
    }
    for (int m = 0; m < MC; m++) list[n++] = g[m];
    nkb = n;
  }
  size_t base = ((size_t)b * HH + h) * SS * HD;

  int lane = tid & 63;
  int w = tid >> 6;
  int lr = lane & 15;     // fragment m/n index
  int quad = lane >> 4;   // fragment k-group

  // Q fragments (A-layout) straight from global into registers (q pre-scaled).
  short8_t qa[2];
  {
    const unsigned short* qp =
        q + base + (size_t)(l * 64 + w * 16 + lr) * HD + quad * 8;
    qa[0] = *(const short8_t*)qp;
    qa[1] = *(const short8_t*)(qp + 32);
  }

  float4_t Ot[4];
  float ls[4];  // per-lane partial row sums (4 cols/row this lane)
#pragma unroll
  for (int t = 0; t < 4; t++)
#pragma unroll
    for (int r = 0; r < 4; r++) Ot[t][r] = 0.f;
#pragma unroll
  for (int r = 0; r < 4; r++) ls[r] = 0.f;

  // staging: each thread moves 2x16B for K and 2x16B for Vt
  int srow = tid >> 3;          // 0..31
  int scol = (tid & 7) * 8;     // 0..56

  uint4 kr0, kr1, vr0, vr1;
  {
    int kb = list[0];
    const unsigned short* kp = k + base + (size_t)(kb * 64 + srow) * HD + scol;
    const unsigned short* vp = vt + base + (size_t)srow * SS + kb * 64 + scol;
    kr0 = *(const uint4*)kp;
    kr1 = *(const uint4*)(kp + 32 * HD);
    vr0 = *(const uint4*)vp;
    vr1 = *(const uint4*)(vp + 32 * SS);
  }
  // write block 0 into buf 0
  *(uint4*)&Ks[0][srow * LDK + scol] = kr0;
  *(uint4*)&Ks[0][(srow + 32) * LDK + scol] = kr1;
  *(uint4*)&Vs[0][srow * LDK + scol] = vr0;
  *(uint4*)&Vs[0][(srow + 32) * LDK + scol] = vr1;
  int p = 0;

  for (int t = 0; t < nkb; t++) {
    __syncthreads();  // buf[p] writes visible; all waves done reading buf[p^1]

    if (t + 1 < nkb) {  // issue next block's global loads (fly during compute)
      int kb = list[t + 1];
      const unsigned short* kp = k + base + (size_t)(kb * 64 + srow) * HD + scol;
      const unsigned short* vp = vt + base + (size_t)srow * SS + kb * 64 + scol;
      kr0 = *(const uint4*)kp;
      kr1 = *(const uint4*)(kp + 32 * HD);
      vr0 = *(const uint4*)vp;
      vr1 = *(const uint4*)(vp + 32 * SS);
    }

    // S = Q K^T
    float4_t st[4];
#pragma unroll
    for (int tt = 0; tt < 4; tt++) {
#pragma unroll
      for (int r = 0; r < 4; r++) st[tt][r] = 0.f;
      short8_t kb0 = *(const short8_t*)&Ks[p][(tt * 16 + lr) * LDK + quad * 8];
      short8_t kb1 =
          *(const short8_t*)&Ks[p][(tt * 16 + lr) * LDK + quad * 8 + 32];
      st[tt] = __builtin_amdgcn_mfma_f32_16x16x32_bf16(qa[0], kb0, st[tt], 0, 0, 0);
      st[tt] = __builtin_amdgcn_mfma_f32_16x16x32_bf16(qa[1], kb1, st[tt], 0, 0, 0);
    }

    // fixed-max softmax: p = exp(s); per-lane partial sums, no shuffles.
#pragma unroll
    for (int tt = 0; tt < 4; tt++)
#pragma unroll
      for (int r = 0; r < 4; r++) {
        float pv = __expf(st[tt][r]);
        st[tt][r] = pv;
        ls[r] += pv;
        Ps[w][(quad * 4 + r) * LDK + tt * 16 + lr] = f2bf(pv);
      }

    // O += P V
#pragma unroll
    for (int s = 0; s < 2; s++) {
      short8_t pa = *(const short8_t*)&Ps[w][lr * LDK + s * 32 + quad * 8];
#pragma unroll
      for (int tt = 0; tt < 4; tt++) {
        short8_t vb =
            *(const short8_t*)&Vs[p][(tt * 16 + lr) * LDK + s * 32 + quad * 8];
        Ot[tt] = __builtin_amdgcn_mfma_f32_16x16x32_bf16(pa, vb, Ot[tt], 0, 0, 0);
      }
    }

    if (t + 1 < nkb) {  // write prefetched regs into the other buffer
      *(uint4*)&Ks[p ^ 1][srow * LDK + scol] = kr0;
      *(uint4*)&Ks[p ^ 1][(srow + 32) * LDK + scol] = kr1;
      *(uint4*)&Vs[p ^ 1][srow * LDK + scol] = vr0;
      *(uint4*)&Vs[p ^ 1][(srow + 32) * LDK + scol] = vr1;
    }
    p ^= 1;
  }

  // reduce row sums across the 16 lanes holding each row
#pragma unroll
  for (int r = 0; r < 4; r++)
#pragma unroll
    for (int off = 1; off < 16; off <<= 1) ls[r] += __shfl_xor(ls[r], off);

  if (!heavy) {
#pragma unroll
    for (int r = 0; r < 4; r++) {
      float inv = 1.f / ls[r];
      size_t row = (size_t)b * SS + (size_t)l * 64 + w * 16 + quad * 4 + r;
#pragma unroll
      for (int tt = 0; tt < 4; tt++)
        ctxb[row * DD + h * HD + tt * 16 + lr] = f2bf(Ot[tt][r] * inv);
    }
  } else {
    float* pb = part + ((size_t)hid * 8 + chunk) * 4160;  // 64*64 O + 64 lsum
#pragma unroll
    for (int r = 0; r < 4; r++) {
      int rowi = w * 16 + quad * 4 + r;
#pragma unroll
      for (int tt = 0; tt < 4; tt++)
        pb[rowi * 64 + tt * 16 + lr] = Ot[tt][r];
      if (lr == 0) pb[4096 + rowi] = ls[r];
    }
  }
}

// ---------------------------------------------------------------------------
// Combine the 8 partials of each heavy block, normalize, write bf16 ctx.
// ---------------------------------------------------------------------------
__global__ __launch_bounds__(256) void reduce_heavy(
    const float* __restrict__ part, unsigned short* __restrict__ ctxb) {
  __shared__ float lrow[64];
  int hid = blockIdx.x;
  int tid = threadIdx.x;
  int b = hid / 24;
  int r = hid % 24;
  int h = r >> 1;
  int l = (r & 1) ? (NBK - 1) : 0;
  const float* pb = part + (size_t)hid * 8 * 4160;
  if (tid < 64) {
    float s = 0.f;
#pragma unroll
    for (int c = 0; c < 8; c++) s += pb[c * 4160 + 4096 + tid];
    lrow[tid] = s;
  }
  __syncthreads();
#pragma unroll
  for (int e = tid; e < 4096; e += 256) {
    float o = 0.f;
#pragma unroll
    for (int c = 0; c < 8; c++) o += pb[c * 4160 + e];
    int rowi = e >> 6, col = e & 63;
    size_t row = (size_t)b * SS + (size_t)l * 64 + rowi;
    ctxb[row * DD + h * HD + col] = f2bf(o / lrow[rowi]);
  }
}

extern "C" void kernel_launch(void* const* d_in, const int* in_sizes, int n_in,
                              void* d_out, int out_size, void* d_ws,
                              size_t ws_size, hipStream_t stream) {
  const float* hs = (const float*)d_in[0];
  const float* Wq = (const float*)d_in[1];
  const float* Wk = (const float*)d_in[2];
  const float* Wv = (const float*)d_in[3];
  const float* Wo = (const float*)d_in[4];
  const int* graph = (const int*)d_in[10];

  const size_t NHS = (size_t)BB * SS * DD;  // 6291456
  unsigned short* hsb = (unsigned short*)d_ws;
  unsigned short* wqkvb = hsb + NHS;            // 3*768*768
  unsigned short* wob = wqkvb + 3 * 768 * 768;  // 768*768
  unsigned short* qb = wob + 768 * 768;
  unsigned short* kb = qb + NHS;
  unsigned short* vtb = kb + NHS;
  unsigned short* ctxb = vtb + NHS;
  float* part = (float*)(ctxb + NHS);  // 48*8*4160 floats

  cvt_all<<<8448, 256, 0, stream>>>(hs, Wq, Wk, Wv, Wo, hsb, wqkvb, wob);
  gemm_qkv_b<<<dim3(64, 18, 1), 256, 0, stream>>>(hsb, wqkvb, qb, kb, vtb);
  attn2<<<1872, 256, 0, stream>>>(qb, kb, vtb, graph, ctxb, part);
  reduce_heavy<<<48, 256, 0, stream>>>(part, ctxb);
  gemm_out_b<<<dim3(64, 6, 1), 256, 0, stream>>>(ctxb, wob, (float*)d_out);
}

// Round 6
// 209.494 us; speedup vs baseline: 1.8385x; 1.0452x over previous
//
#include <hip/hip_runtime.h>
#include <hip/hip_bf16.h>

#define BB 2
#define HH 12
#define SS 4096
#define DD 768
#define HD 64
#define NBK 64
#define MC 3

typedef __attribute__((ext_vector_type(8))) short short8_t;
typedef __attribute__((ext_vector_type(4))) float float4_t;

__device__ __forceinline__ unsigned short f2bf(float f) {
  union { float f; unsigned u; } c;
  c.f = f;
  unsigned u = c.u + 0x7FFFu + ((c.u >> 16) & 1u);  // RNE
  return (unsigned short)(u >> 16);
}

// async 16B global -> LDS (gfx950). LDS dest = wave-uniform base + lane*16.
__device__ __forceinline__ void gload16(const unsigned short* gp,
                                        unsigned short* lp) {
  __builtin_amdgcn_global_load_lds(
      (const __attribute__((address_space(1))) unsigned int*)gp,
      (__attribute__((address_space(3))) unsigned int*)lp, 16, 0, 0);
}

#define LDK 72  // padded stride (attn kernel only)

// ---------------------------------------------------------------------------
// One-shot fp32 -> bf16 conversion: hs (8192x768), Wq|Wk|Wv packed (2304x768),
// Wo (768x768). One float4 per thread.
// ---------------------------------------------------------------------------
__global__ __launch_bounds__(256) void cvt_all(
    const float* __restrict__ hs, const float* __restrict__ Wq,
    const float* __restrict__ Wk, const float* __restrict__ Wv,
    const float* __restrict__ Wo, unsigned short* __restrict__ hsb,
    unsigned short* __restrict__ wqkvb, unsigned short* __restrict__ wob) {
  long i4 = (long)blockIdx.x * 256 + threadIdx.x;  // float4 index
  const float* src;
  unsigned short* dst;
  if (i4 < 1572864) {          // hs: 6291456 floats
    src = hs + i4 * 4;
    dst = hsb + i4 * 4;
  } else {
    long r = i4 - 1572864;
    int w = (int)(r / 147456);  // 0..3 : Wq,Wk,Wv,Wo (589824 floats each)
    long e = r % 147456;
    src = (w == 0 ? Wq : w == 1 ? Wk : w == 2 ? Wv : Wo) + e * 4;
    dst = (w < 3) ? (wqkvb + (long)w * 589824 + e * 4) : (wob + e * 4);
  }
  float4_t v = *(const float4_t*)src;
  uint2 p;
  p.x = (unsigned)f2bf(v[0]) | ((unsigned)f2bf(v[1]) << 16);
  p.y = (unsigned)f2bf(v[2]) | ((unsigned)f2bf(v[3]) << 16);
  *(uint2*)dst = p;
}

// ---------------------------------------------------------------------------
// GEMM: round-0's proven structure (BK=64, 128-B LDS rows, XOR swizzle
// slot=c^(r&7) -> measured 0 bank conflicts, gload_lds staging, single
// __syncthreads per K-iter) with BN shrunk 128->64:
//   LDS = As 32 KB + Bs 16 KB = 48 KB -> 3 blocks/CU (vs 2), 12 waves/CU.
//   qkv grid 64x36 = 2304 blocks = exactly 3.0 full rounds of 768 resident
//   (round-0's 1152 @ 2/CU = 2.25 rounds -> 28%-full tail round).
// Per wave: 32x64 output, acc 32 VGPR (total ~80: no spill at plain
// __launch_bounds__(256); rounds 2/3 proved min-wave hints force spill).
// ---------------------------------------------------------------------------
#define STAGE_T(buf_, A_, B_, m0_, n0_, kt_)                                  \
  {                                                                           \
    int rr_ = lane >> 3;                                                      \
    int cg_ = (lane & 7) ^ rr_;                                               \
    _Pragma("unroll") for (int u = 0; u < 4; u++) {                           \
      int g_ = w * 4 + u;                                                     \
      gload16(A_ + (size_t)(m0_ + g_ * 8 + rr_) * DD + kt_ + cg_ * 8,         \
              &As[buf_][g_ * 512]);                                           \
    }                                                                         \
    _Pragma("unroll") for (int u = 0; u < 2; u++) {                           \
      int g_ = w * 2 + u;                                                     \
      gload16(B_ + (size_t)(n0_ + g_ * 8 + rr_) * DD + kt_ + cg_ * 8,         \
              &Bs[buf_][g_ * 512]);                                           \
    }                                                                         \
  }

#define LOAD_FRAGS2(buf_, kk_)                                                \
  int cb = qd + ((kk_) >> 3);                                                 \
  short8_t af[2], bfr[4];                                                     \
  _Pragma("unroll") for (int i = 0; i < 2; i++) {                             \
    int r_ = wm + i * 16 + fr;                                                \
    af[i] = *(const short8_t*)&As[buf_][r_ * 64 + (cb ^ (fr & 7)) * 8];       \
  }                                                                           \
  _Pragma("unroll") for (int j = 0; j < 4; j++) {                             \
    int r_ = j * 16 + fr;                                                     \
    bfr[j] = *(const short8_t*)&Bs[buf_][r_ * 64 + (cb ^ (fr & 7)) * 8];      \
  }

// ---------------------------------------------------------------------------
// QKV projection, bf16 inputs, dbuf async staging, 1 barrier/iter.
// Q/K tiles: SWAPPED operands (C^T, reg dim spans d) -> packed uint2 stores.
// V: normal orientation (reg dim spans s) -> packed uint2 stores transposed.
// ---------------------------------------------------------------------------
__global__ __launch_bounds__(256) void gemm_qkv_b(
    const unsigned short* __restrict__ A, const unsigned short* __restrict__ W,
    unsigned short* __restrict__ qb, unsigned short* __restrict__ kb,
    unsigned short* __restrict__ vtb) {
  __shared__ unsigned short As[2][128 * 64];  // 32 KB
  __shared__ unsigned short Bs[2][64 * 64];   // 16 KB
  int tid = threadIdx.x;
  int m0 = blockIdx.x * 128;
  int n0 = blockIdx.y * 64;   // 0..2240; 64 | 768 so never straddles
  int lane = tid & 63;
  int w = tid >> 6;
  int wm = w * 32;            // 4 waves x 32 rows; all waves span 64 cols
  int fr = lane & 15;
  int qd = lane >> 4;
  int ysel = n0 / 768;

  float4_t acc[8];
#pragma unroll
  for (int i = 0; i < 8; i++)
#pragma unroll
    for (int r = 0; r < 4; r++) acc[i][r] = 0.f;

  STAGE_T(0, A, W, m0, n0, 0)
  int p = 0;

  if (ysel < 2) {
    // ---- Q/K: swapped-operand K-loop; acc[j*2+i] = C^T tile ----
    for (int kt = 0; kt < DD; kt += 64) {
      __syncthreads();  // drains stage(kt); waves done reading buf p^1
      if (kt + 64 < DD) STAGE_T(p ^ 1, A, W, m0, n0, kt + 64)
#pragma unroll
      for (int kk = 0; kk < 64; kk += 32) {
        LOAD_FRAGS2(p, kk)
#pragma unroll
        for (int i = 0; i < 2; i++)
#pragma unroll
          for (int j = 0; j < 4; j++)
            acc[j * 2 + i] = __builtin_amdgcn_mfma_f32_16x16x32_bf16(
                bfr[j], af[i], acc[j * 2 + i], 0, 0, 0);
      }
      p ^= 1;
    }
    int cn = lane & 15;
    int quad = lane >> 4;
    float scale = (ysel == 0) ? 0.125f : 1.0f;  // fold 1/sqrt(64) into Q
    unsigned short* dst = (ysel == 0) ? qb : kb;
    int nb0 = n0 - ysel * 768;
#pragma unroll
    for (int j = 0; j < 4; j++)
#pragma unroll
      for (int i = 0; i < 2; i++) {
        int m = m0 + wm + i * 16 + cn;         // s dimension
        int nn = nb0 + j * 16 + quad * 4;      // d dimension (4-consec)
        int b = m >> 12, s = m & 4095;
        int h = nn >> 6, d0 = nn & 63;
        uint2 pk;
        pk.x = (unsigned)f2bf(acc[j * 2 + i][0] * scale) |
               ((unsigned)f2bf(acc[j * 2 + i][1] * scale) << 16);
        pk.y = (unsigned)f2bf(acc[j * 2 + i][2] * scale) |
               ((unsigned)f2bf(acc[j * 2 + i][3] * scale) << 16);
        *(uint2*)&dst[(((size_t)b * HH + h) * SS + s) * HD + d0] = pk;
      }
  } else {
    // ---- V: normal K-loop; reg dim spans s (contig in [b][h][d][s]) ----
    for (int kt = 0; kt < DD; kt += 64) {
      __syncthreads();
      if (kt + 64 < DD) STAGE_T(p ^ 1, A, W, m0, n0, kt + 64)
#pragma unroll
      for (int kk = 0; kk < 64; kk += 32) {
        LOAD_FRAGS2(p, kk)
#pragma unroll
        for (int i = 0; i < 2; i++)
#pragma unroll
          for (int j = 0; j < 4; j++)
            acc[i * 4 + j] = __builtin_amdgcn_mfma_f32_16x16x32_bf16(
                af[i], bfr[j], acc[i * 4 + j], 0, 0, 0);
      }
      p ^= 1;
    }
    int cn = lane & 15;
    int quad = lane >> 4;
    int nb0 = n0 - 1536;
#pragma unroll
    for (int i = 0; i < 2; i++)
#pragma unroll
      for (int j = 0; j < 4; j++) {
        int m = m0 + wm + i * 16 + quad * 4;   // s base (4-consec)
        int nn = nb0 + j * 16 + cn;            // d dimension
        int b = m >> 12, s0 = m & 4095;
        int h = nn >> 6, d = nn & 63;
        uint2 pk;
        pk.x = (unsigned)f2bf(acc[i * 4 + j][0]) |
               ((unsigned)f2bf(acc[i * 4 + j][1]) << 16);
        pk.y = (unsigned)f2bf(acc[i * 4 + j][2]) |
               ((unsigned)f2bf(acc[i * 4 + j][3]) << 16);
        *(uint2*)&vtb[(((size_t)b * HH + h) * HD + d) * SS + s0] = pk;
      }
  }
}

// ---------------------------------------------------------------------------
// Output projection, bf16 inputs, fp32 output (coalesced), same structure.
// Grid 64x12 = 768 blocks = exactly one full resident round at 3/CU.
// ---------------------------------------------------------------------------
__global__ __launch_bounds__(256) void gemm_out_b(
    const unsigned short* __restrict__ A, const unsigned short* __restrict__ W,
    float* __restrict__ dst) {
  __shared__ unsigned short As[2][128 * 64];
  __shared__ unsigned short Bs[2][64 * 64];
  int tid = threadIdx.x;
  int m0 = blockIdx.x * 128;
  int n0 = blockIdx.y * 64;
  int lane = tid & 63;
  int w = tid >> 6;
  int wm = w * 32;
  int fr = lane & 15;
  int qd = lane >> 4;

  float4_t acc[8];
#pragma unroll
  for (int i = 0; i < 8; i++)
#pragma unroll
    for (int r = 0; r < 4; r++) acc[i][r] = 0.f;

  STAGE_T(0, A, W, m0, n0, 0)
  int p = 0;
  for (int kt = 0; kt < DD; kt += 64) {
    __syncthreads();
    if (kt + 64 < DD) STAGE_T(p ^ 1, A, W, m0, n0, kt + 64)
#pragma unroll
    for (int kk = 0; kk < 64; kk += 32) {
      LOAD_FRAGS2(p, kk)
#pragma unroll
      for (int i = 0; i < 2; i++)
#pragma unroll
        for (int j = 0; j < 4; j++)
          acc[i * 4 + j] = __builtin_amdgcn_mfma_f32_16x16x32_bf16(
              af[i], bfr[j], acc[i * 4 + j], 0, 0, 0);
    }
    p ^= 1;
  }

  int cn = lane & 15;
  int rb = (lane >> 4) * 4;
#pragma unroll
  for (int i = 0; i < 2; i++)
#pragma unroll
    for (int j = 0; j < 4; j++)
#pragma unroll
      for (int r = 0; r < 4; r++) {
        int m = m0 + wm + i * 16 + rb + r;
        int n = n0 + j * 16 + cn;
        dst[(size_t)m * DD + n] = acc[i * 4 + j][r];
      }
}

// ---------------------------------------------------------------------------
// Block-sparse attention, fixed-max softmax, dbuf K/V LDS, 1 barrier/iter.
// Heavy blocks (l=0,63) split 8 ways -> partial O + rowsum to scratch.
// Grid: ids 0..383 heavy chunks, 384..1871 lights.
// ---------------------------------------------------------------------------
__global__ __launch_bounds__(256) void attn2(
    const unsigned short* __restrict__ q, const unsigned short* __restrict__ k,
    const unsigned short* __restrict__ vt, const int* __restrict__ graph,
    unsigned short* __restrict__ ctxb, float* __restrict__ part) {
  __shared__ unsigned short Ks[2][64 * LDK];   // K[key][d]
  __shared__ unsigned short Vs[2][64 * LDK];   // V^T[d][key]
  __shared__ unsigned short Ps[4][16 * LDK];   // per-wave P[q][key]

  int tid = threadIdx.x;
  int id = blockIdx.x;
  int b, h, l, nkb, heavy, chunk = 0, hid = 0;
  int list[8];
  if (id < 384) {
    heavy = 1;
    hid = id >> 3;
    chunk = id & 7;
    b = hid / 24;
    int r = hid % 24;
    h = r >> 1;
    l = (r & 1) ? (NBK - 1) : 0;
    nkb = 8;
#pragma unroll
    for (int i = 0; i < 8; i++) list[i] = chunk * 8 + i;
  } else {
    heavy = 0;
    int j = id - 384;
    b = j / 744;  // 744 = 12*62
    int r = j % 744;
    h = r / 62;
    l = 1 + r % 62;
    const int* g = graph + (((size_t)b * HH + h) * NBK + l) * MC;
    int n = 0;
    if (l == 1) {
      list[0] = 0; list[1] = 1; list[2] = 2; list[3] = NBK - 1; n = 4;
    } else if (l == NBK - 2) {
      list[0] = 0; list[1] = NBK - 3; list[2] = NBK - 2; list[3] = NBK - 1; n = 4;
    } else {
      list[0] = 0; list[1] = l - 1; list[2] = l; list[3] = l + 1;
      list[4] = NBK - 1; n = 5;
    }
    for (int m = 0; m < MC; m++) list[n++] = g[m];
    nkb = n;
  }
  size_t base = ((size_t)b * HH + h) * SS * HD;

  int lane = tid & 63;
  int w = tid >> 6;
  int lr = lane & 15;     // fragment m/n index
  int quad = lane >> 4;   // fragment k-group

  // Q fragments (A-layout) straight from global into registers (q pre-scaled).
  short8_t qa[2];
  {
    const unsigned short* qp =
        q + base + (size_t)(l * 64 + w * 16 + lr) * HD + quad * 8;
    qa[0] = *(const short8_t*)qp;
    qa[1] = *(const short8_t*)(qp + 32);
  }

  float4_t Ot[4];
  float ls[4];  // per-lane partial row sums (4 cols/row this lane)
#pragma unroll
  for (int t = 0; t < 4; t++)
#pragma unroll
    for (int r = 0; r < 4; r++) Ot[t][r] = 0.f;
#pragma unroll
  for (int r = 0; r < 4; r++) ls[r] = 0.f;

  // staging: each thread moves 2x16B for K and 2x16B for Vt
  int srow = tid >> 3;          // 0..31
  int scol = (tid & 7) * 8;     // 0..56

  uint4 kr0, kr1, vr0, vr1;
  {
    int kb = list[0];
    const unsigned short* kp = k + base + (size_t)(kb * 64 + srow) * HD + scol;
    const unsigned short* vp = vt + base + (size_t)srow * SS + kb * 64 + scol;
    kr0 = *(const uint4*)kp;
    kr1 = *(const uint4*)(kp + 32 * HD);
    vr0 = *(const uint4*)vp;
    vr1 = *(const uint4*)(vp + 32 * SS);
  }
  // write block 0 into buf 0
  *(uint4*)&Ks[0][srow * LDK + scol] = kr0;
  *(uint4*)&Ks[0][(srow + 32) * LDK + scol] = kr1;
  *(uint4*)&Vs[0][srow * LDK + scol] = vr0;
  *(uint4*)&Vs[0][(srow + 32) * LDK + scol] = vr1;
  int p = 0;

  for (int t = 0; t < nkb; t++) {
    __syncthreads();  // buf[p] writes visible; all waves done reading buf[p^1]

    if (t + 1 < nkb) {  // issue next block's global loads (fly during compute)
      int kb = list[t + 1];
      const unsigned short* kp = k + base + (size_t)(kb * 64 + srow) * HD + scol;
      const unsigned short* vp = vt + base + (size_t)srow * SS + kb * 64 + scol;
      kr0 = *(const uint4*)kp;
      kr1 = *(const uint4*)(kp + 32 * HD);
      vr0 = *(const uint4*)vp;
      vr1 = *(const uint4*)(vp + 32 * SS);
    }

    // S = Q K^T
    float4_t st[4];
#pragma unroll
    for (int tt = 0; tt < 4; tt++) {
#pragma unroll
      for (int r = 0; r < 4; r++) st[tt][r] = 0.f;
      short8_t kb0 = *(const short8_t*)&Ks[p][(tt * 16 + lr) * LDK + quad * 8];
      short8_t kb1 =
          *(const short8_t*)&Ks[p][(tt * 16 + lr) * LDK + quad * 8 + 32];
      st[tt] = __builtin_amdgcn_mfma_f32_16x16x32_bf16(qa[0], kb0, st[tt], 0, 0, 0);
      st[tt] = __builtin_amdgcn_mfma_f32_16x16x32_bf16(qa[1], kb1, st[tt], 0, 0, 0);
    }

    // fixed-max softmax: p = exp(s); per-lane partial sums, no shuffles.
#pragma unroll
    for (int tt = 0; tt < 4; tt++)
#pragma unroll
      for (int r = 0; r < 4; r++) {
        float pv = __expf(st[tt][r]);
        st[tt][r] = pv;
        ls[r] += pv;
        Ps[w][(quad * 4 + r) * LDK + tt * 16 + lr] = f2bf(pv);
      }

    // O += P V
#pragma unroll
    for (int s = 0; s < 2; s++) {
      short8_t pa = *(const short8_t*)&Ps[w][lr * LDK + s * 32 + quad * 8];
#pragma unroll
      for (int tt = 0; tt < 4; tt++) {
        short8_t vb =
            *(const short8_t*)&Vs[p][(tt * 16 + lr) * LDK + s * 32 + quad * 8];
        Ot[tt] = __builtin_amdgcn_mfma_f32_16x16x32_bf16(pa, vb, Ot[tt], 0, 0, 0);
      }
    }

    if (t + 1 < nkb) {  // write prefetched regs into the other buffer
      *(uint4*)&Ks[p ^ 1][srow * LDK + scol] = kr0;
      *(uint4*)&Ks[p ^ 1][(srow + 32) * LDK + scol] = kr1;
      *(uint4*)&Vs[p ^ 1][srow * LDK + scol] = vr0;
      *(uint4*)&Vs[p ^ 1][(srow + 32) * LDK + scol] = vr1;
    }
    p ^= 1;
  }

  // reduce row sums across the 16 lanes holding each row
#pragma unroll
  for (int r = 0; r < 4; r++)
#pragma unroll
    for (int off = 1; off < 16; off <<= 1) ls[r] += __shfl_xor(ls[r], off);

  if (!heavy) {
#pragma unroll
    for (int r = 0; r < 4; r++) {
      float inv = 1.f / ls[r];
      size_t row = (size_t)b * SS + (size_t)l * 64 + w * 16 + quad * 4 + r;
#pragma unroll
      for (int tt = 0; tt < 4; tt++)
        ctxb[row * DD + h * HD + tt * 16 + lr] = f2bf(Ot[tt][r] * inv);
    }
  } else {
    float* pb = part + ((size_t)hid * 8 + chunk) * 4160;  // 64*64 O + 64 lsum
#pragma unroll
    for (int r = 0; r < 4; r++) {
      int rowi = w * 16 + quad * 4 + r;
#pragma unroll
      for (int tt = 0; tt < 4; tt++)
        pb[rowi * 64 + tt * 16 + lr] = Ot[tt][r];
      if (lr == 0) pb[4096 + rowi] = ls[r];
    }
  }
}

// ---------------------------------------------------------------------------
// Combine the 8 partials of each heavy block, normalize, write bf16 ctx.
// ---------------------------------------------------------------------------
__global__ __launch_bounds__(256) void reduce_heavy(
    const float* __restrict__ part, unsigned short* __restrict__ ctxb) {
  __shared__ float lrow[64];
  int hid = blockIdx.x;
  int tid = threadIdx.x;
  int b = hid / 24;
  int r = hid % 24;
  int h = r >> 1;
  int l = (r & 1) ? (NBK - 1) : 0;
  const float* pb = part + (size_t)hid * 8 * 4160;
  if (tid < 64) {
    float s = 0.f;
#pragma unroll
    for (int c = 0; c < 8; c++) s += pb[c * 4160 + 4096 + tid];
    lrow[tid] = s;
  }
  __syncthreads();
#pragma unroll
  for (int e = tid; e < 4096; e += 256) {
    float o = 0.f;
#pragma unroll
    for (int c = 0; c < 8; c++) o += pb[c * 4160 + e];
    int rowi = e >> 6, col = e & 63;
    size_t row = (size_t)b * SS + (size_t)l * 64 + rowi;
    ctxb[row * DD + h * HD + col] = f2bf(o / lrow[rowi]);
  }
}

extern "C" void kernel_launch(void* const* d_in, const int* in_sizes, int n_in,
                              void* d_out, int out_size, void* d_ws,
                              size_t ws_size, hipStream_t stream) {
  const float* hs = (const float*)d_in[0];
  const float* Wq = (const float*)d_in[1];
  const float* Wk = (const float*)d_in[2];
  const float* Wv = (const float*)d_in[3];
  const float* Wo = (const float*)d_in[4];
  const int* graph = (const int*)d_in[10];

  const size_t NHS = (size_t)BB * SS * DD;  // 6291456
  unsigned short* hsb = (unsigned short*)d_ws;
  unsigned short* wqkvb = hsb + NHS;            // 3*768*768
  unsigned short* wob = wqkvb + 3 * 768 * 768;  // 768*768
  unsigned short* qb = wob + 768 * 768;
  unsigned short* kb = qb + NHS;
  unsigned short* vtb = kb + NHS;
  unsigned short* ctxb = vtb + NHS;
  float* part = (float*)(ctxb + NHS);  // 48*8*4160 floats

  cvt_all<<<8448, 256, 0, stream>>>(hs, Wq, Wk, Wv, Wo, hsb, wqkvb, wob);
  gemm_qkv_b<<<dim3(64, 36, 1), 256, 0, stream>>>(hsb, wqkvb, qb, kb, vtb);
  attn2<<<1872, 256, 0, stream>>>(qb, kb, vtb, graph, ctxb, part);
  reduce_heavy<<<48, 256, 0, stream>>>(part, ctxb);
  gemm_out_b<<<dim3(64, 12, 1), 256, 0, stream>>>(ctxb, wob, (float*)d_out);
}

// Round 7
// 199.521 us; speedup vs baseline: 1.9304x; 1.0500x over previous
//
#include <hip/hip_runtime.h>
#include <hip/hip_bf16.h>
#include <hip/hip_cooperative_groups.h>

namespace cg = cooperative_groups;

#define BB 2
#define HH 12
#define SS 4096
#define DD 768
#define HD 64
#define NBK 64
#define MC 3
#define LDK 72

typedef __attribute__((ext_vector_type(8))) short short8_t;
typedef __attribute__((ext_vector_type(4))) float float4_t;

__device__ __forceinline__ unsigned short f2bf(float f) {
  union { float f; unsigned u; } c;
  c.f = f;
  unsigned u = c.u + 0x7FFFu + ((c.u >> 16) & 1u);  // RNE
  return (unsigned short)(u >> 16);
}

// async 16B global -> LDS (gfx950). LDS dest = wave-uniform base + lane*16.
__device__ __forceinline__ void gload16(const unsigned short* gp,
                                        unsigned short* lp) {
  __builtin_amdgcn_global_load_lds(
      (const __attribute__((address_space(1))) unsigned int*)gp,
      (__attribute__((address_space(3))) unsigned int*)lp, 16, 0, 0);
}

// ===========================================================================
// FUSED cooperative kernel: cvt -> qkv -> attn -> reduce -> out with
// grid.sync() between phases. Rationale: sum of measured kernel durations
// (<=125us) is far below total dur (209us); the residual is per-launch
// boundary cost of the 5-kernel chain. One kernel removes 4 boundaries.
// LDS: 48KB union -> 3 blocks/CU; grid = occupancy*256CU (grid-stride
// phases are grid-size agnostic). Phase bodies = round-6 proven code.
// ===========================================================================

// ---- gemm core: BM=128 BN=64 BK=64, dbuf, swizzle slot=c^(r&7) (0-conflict)
__device__ __forceinline__ void stage_ab(unsigned short* AsB, unsigned short* BsB,
                                         const unsigned short* A,
                                         const unsigned short* B, int m0,
                                         int n0, int kt, int lane, int w) {
  int rr = lane >> 3;
  int cgx = (lane & 7) ^ rr;
#pragma unroll
  for (int u = 0; u < 4; u++) {
    int g = w * 4 + u;
    gload16(A + (size_t)(m0 + g * 8 + rr) * DD + kt + cgx * 8, AsB + g * 512);
  }
#pragma unroll
  for (int u = 0; u < 2; u++) {
    int g = w * 2 + u;
    gload16(B + (size_t)(n0 + g * 8 + rr) * DD + kt + cgx * 8, BsB + g * 512);
  }
}

template <int SWAP>
__device__ __forceinline__ void gemm_core(const unsigned short* A,
                                          const unsigned short* B, int m0,
                                          int n0, unsigned short* smem,
                                          int tid, float4_t acc[8]) {
  unsigned short* As = smem;           // 2 x 8192 shorts (32 KB)
  unsigned short* Bs = smem + 16384;   // 2 x 4096 shorts (16 KB)
  int lane = tid & 63;
  int w = tid >> 6;
  int wm = w * 32;
  int fr = lane & 15;
  int qd = lane >> 4;
#pragma unroll
  for (int i = 0; i < 8; i++)
#pragma unroll
    for (int r = 0; r < 4; r++) acc[i][r] = 0.f;
  __syncthreads();  // LDS reuse guard (previous virtual tile fully done)
  stage_ab(As, Bs, A, B, m0, n0, 0, lane, w);
  int p = 0;
  for (int kt = 0; kt < DD; kt += 64) {
    __syncthreads();  // drains stage(kt); all waves done reading buf p^1
    if (kt + 64 < DD)
      stage_ab(As + (p ^ 1) * 8192, Bs + (p ^ 1) * 4096, A, B, m0, n0, kt + 64,
               lane, w);
#pragma unroll
    for (int kk = 0; kk < 64; kk += 32) {
      int cb = qd + (kk >> 3);
      short8_t af[2], bfr[4];
#pragma unroll
      for (int i = 0; i < 2; i++) {
        int r_ = wm + i * 16 + fr;
        af[i] =
            *(const short8_t*)&As[p * 8192 + r_ * 64 + (cb ^ (fr & 7)) * 8];
      }
#pragma unroll
      for (int j = 0; j < 4; j++) {
        int r_ = j * 16 + fr;
        bfr[j] =
            *(const short8_t*)&Bs[p * 4096 + r_ * 64 + (cb ^ (fr & 7)) * 8];
      }
#pragma unroll
      for (int i = 0; i < 2; i++)
#pragma unroll
        for (int j = 0; j < 4; j++) {
          if (SWAP)
            acc[j * 2 + i] = __builtin_amdgcn_mfma_f32_16x16x32_bf16(
                bfr[j], af[i], acc[j * 2 + i], 0, 0, 0);
          else
            acc[i * 4 + j] = __builtin_amdgcn_mfma_f32_16x16x32_bf16(
                af[i], bfr[j], acc[i * 4 + j], 0, 0, 0);
        }
    }
    p ^= 1;
  }
}

__device__ __forceinline__ void qkv_tile(int vb, const unsigned short* hsb,
                                         const unsigned short* wqkvb,
                                         unsigned short* qb,
                                         unsigned short* kb,
                                         unsigned short* vtb,
                                         unsigned short* smem, int tid) {
  int m0 = (vb & 63) * 128;
  int n0 = (vb >> 6) * 64;  // 64 | 768, never straddles
  int ysel = n0 / 768;
  int lane = tid & 63;
  int w = tid >> 6;
  int wm = w * 32;
  float4_t acc[8];
  if (ysel < 2) {
    gemm_core<1>(hsb, wqkvb, m0, n0, smem, tid, acc);
    int cn = lane & 15;
    int quad = lane >> 4;
    float scale = (ysel == 0) ? 0.125f : 1.0f;  // fold 1/sqrt(64) into Q
    unsigned short* dst = (ysel == 0) ? qb : kb;
    int nb0 = n0 - ysel * 768;
#pragma unroll
    for (int j = 0; j < 4; j++)
#pragma unroll
      for (int i = 0; i < 2; i++) {
        int m = m0 + wm + i * 16 + cn;       // s dimension
        int nn = nb0 + j * 16 + quad * 4;    // d dimension (4-consec)
        int b = m >> 12, s = m & 4095;
        int h = nn >> 6, d0 = nn & 63;
        uint2 pk;
        pk.x = (unsigned)f2bf(acc[j * 2 + i][0] * scale) |
               ((unsigned)f2bf(acc[j * 2 + i][1] * scale) << 16);
        pk.y = (unsigned)f2bf(acc[j * 2 + i][2] * scale) |
               ((unsigned)f2bf(acc[j * 2 + i][3] * scale) << 16);
        *(uint2*)&dst[(((size_t)b * HH + h) * SS + s) * HD + d0] = pk;
      }
  } else {
    gemm_core<0>(hsb, wqkvb, m0, n0, smem, tid, acc);
    int cn = lane & 15;
    int quad = lane >> 4;
    int nb0 = n0 - 1536;
#pragma unroll
    for (int i = 0; i < 2; i++)
#pragma unroll
      for (int j = 0; j < 4; j++) {
        int m = m0 + wm + i * 16 + quad * 4;  // s base (4-consec)
        int nn = nb0 + j * 16 + cn;           // d dimension
        int b = m >> 12, s0 = m & 4095;
        int h = nn >> 6, d = nn & 63;
        uint2 pk;
        pk.x = (unsigned)f2bf(acc[i * 4 + j][0]) |
               ((unsigned)f2bf(acc[i * 4 + j][1]) << 16);
        pk.y = (unsigned)f2bf(acc[i * 4 + j][2]) |
               ((unsigned)f2bf(acc[i * 4 + j][3]) << 16);
        *(uint2*)&vtb[(((size_t)b * HH + h) * HD + d) * SS + s0] = pk;
      }
  }
}

__device__ __forceinline__ void out_tile(int vb, const unsigned short* ctxb,
                                         const unsigned short* wob,
                                         float* dst, unsigned short* smem,
                                         int tid) {
  int m0 = (vb & 63) * 128;
  int n0 = (vb >> 6) * 64;
  float4_t acc[8];
  gemm_core<0>(ctxb, wob, m0, n0, smem, tid, acc);
  int lane = tid & 63;
  int w = tid >> 6;
  int wm = w * 32;
  int cn = lane & 15;
  int rb = (lane >> 4) * 4;
#pragma unroll
  for (int i = 0; i < 2; i++)
#pragma unroll
    for (int j = 0; j < 4; j++)
#pragma unroll
      for (int r = 0; r < 4; r++) {
        int m = m0 + wm + i * 16 + rb + r;
        int n = n0 + j * 16 + cn;
        dst[(size_t)m * DD + n] = acc[i * 4 + j][r];
      }
}

__device__ __forceinline__ void attn_one(int id, const unsigned short* q,
                                         const unsigned short* k,
                                         const unsigned short* vt,
                                         const int* graph,
                                         unsigned short* ctxb, float* part,
                                         unsigned short* smem, int tid) {
  unsigned short* Ks = smem;                 // [2][64*LDK]
  unsigned short* Vs = smem + 2 * 64 * LDK;  // [2][64*LDK]
  unsigned short* Ps = smem + 4 * 64 * LDK;  // [4][16*LDK]
  int b, h, l, nkb, heavy, chunk = 0, hid = 0;
  int list[8];
  if (id < 384) {
    heavy = 1;
    hid = id >> 3;
    chunk = id & 7;
    b = hid / 24;
    int r = hid % 24;
    h = r >> 1;
    l = (r & 1) ? (NBK - 1) : 0;
    nkb = 8;
#pragma unroll
    for (int i = 0; i < 8; i++) list[i] = chunk * 8 + i;
  } else {
    heavy = 0;
    int j = id - 384;
    b = j / 744;  // 744 = 12*62
    int r = j % 744;
    h = r / 62;
    l = 1 + r % 62;
    const int* g = graph + (((size_t)b * HH + h) * NBK + l) * MC;
    int n = 0;
    if (l == 1) {
      list[0] = 0; list[1] = 1; list[2] = 2; list[3] = NBK - 1; n = 4;
    } else if (l == NBK - 2) {
      list[0] = 0; list[1] = NBK - 3; list[2] = NBK - 2; list[3] = NBK - 1;
      n = 4;
    } else {
      list[0] = 0; list[1] = l - 1; list[2] = l; list[3] = l + 1;
      list[4] = NBK - 1; n = 5;
    }
    for (int m = 0; m < MC; m++) list[n++] = g[m];
    nkb = n;
  }
  size_t base = ((size_t)b * HH + h) * SS * HD;

  int lane = tid & 63;
  int w = tid >> 6;
  int lr = lane & 15;
  int quad = lane >> 4;

  // Q fragments straight from global (q pre-scaled).
  short8_t qa[2];
  {
    const unsigned short* qp =
        q + base + (size_t)(l * 64 + w * 16 + lr) * HD + quad * 8;
    qa[0] = *(const short8_t*)qp;
    qa[1] = *(const short8_t*)(qp + 32);
  }

  float4_t Ot[4];
  float ls[4];
#pragma unroll
  for (int t = 0; t < 4; t++)
#pragma unroll
    for (int r = 0; r < 4; r++) Ot[t][r] = 0.f;
#pragma unroll
  for (int r = 0; r < 4; r++) ls[r] = 0.f;

  int srow = tid >> 3;
  int scol = (tid & 7) * 8;

  uint4 kr0, kr1, vr0, vr1;
  {
    int kb = list[0];
    const unsigned short* kp = k + base + (size_t)(kb * 64 + srow) * HD + scol;
    const unsigned short* vp = vt + base + (size_t)srow * SS + kb * 64 + scol;
    kr0 = *(const uint4*)kp;
    kr1 = *(const uint4*)(kp + 32 * HD);
    vr0 = *(const uint4*)vp;
    vr1 = *(const uint4*)(vp + 32 * SS);
  }
  __syncthreads();  // LDS reuse guard vs previous virtual block
  *(uint4*)&Ks[srow * LDK + scol] = kr0;
  *(uint4*)&Ks[(srow + 32) * LDK + scol] = kr1;
  *(uint4*)&Vs[srow * LDK + scol] = vr0;
  *(uint4*)&Vs[(srow + 32) * LDK + scol] = vr1;
  int p = 0;

  for (int t = 0; t < nkb; t++) {
    __syncthreads();

    if (t + 1 < nkb) {
      int kb = list[t + 1];
      const unsigned short* kp =
          k + base + (size_t)(kb * 64 + srow) * HD + scol;
      const unsigned short* vp =
          vt + base + (size_t)srow * SS + kb * 64 + scol;
      kr0 = *(const uint4*)kp;
      kr1 = *(const uint4*)(kp + 32 * HD);
      vr0 = *(const uint4*)vp;
      vr1 = *(const uint4*)(vp + 32 * SS);
    }

    // S = Q K^T
    float4_t st[4];
#pragma unroll
    for (int tt = 0; tt < 4; tt++) {
#pragma unroll
      for (int r = 0; r < 4; r++) st[tt][r] = 0.f;
      short8_t kb0 =
          *(const short8_t*)&Ks[p * 4608 + (tt * 16 + lr) * LDK + quad * 8];
      short8_t kb1 = *(const short8_t*)&Ks[p * 4608 + (tt * 16 + lr) * LDK +
                                           quad * 8 + 32];
      st[tt] =
          __builtin_amdgcn_mfma_f32_16x16x32_bf16(qa[0], kb0, st[tt], 0, 0, 0);
      st[tt] =
          __builtin_amdgcn_mfma_f32_16x16x32_bf16(qa[1], kb1, st[tt], 0, 0, 0);
    }

    // fixed-max softmax
#pragma unroll
    for (int tt = 0; tt < 4; tt++)
#pragma unroll
      for (int r = 0; r < 4; r++) {
        float pv = __expf(st[tt][r]);
        st[tt][r] = pv;
        ls[r] += pv;
        Ps[w * 1152 + (quad * 4 + r) * LDK + tt * 16 + lr] = f2bf(pv);
      }

    // O += P V
#pragma unroll
    for (int s = 0; s < 2; s++) {
      short8_t pa =
          *(const short8_t*)&Ps[w * 1152 + lr * LDK + s * 32 + quad * 8];
#pragma unroll
      for (int tt = 0; tt < 4; tt++) {
        short8_t vb = *(const short8_t*)&Vs[p * 4608 + (tt * 16 + lr) * LDK +
                                            s * 32 + quad * 8];
        Ot[tt] =
            __builtin_amdgcn_mfma_f32_16x16x32_bf16(pa, vb, Ot[tt], 0, 0, 0);
      }
    }

    if (t + 1 < nkb) {
      int pn = p ^ 1;
      *(uint4*)&Ks[pn * 4608 + srow * LDK + scol] = kr0;
      *(uint4*)&Ks[pn * 4608 + (srow + 32) * LDK + scol] = kr1;
      *(uint4*)&Vs[pn * 4608 + srow * LDK + scol] = vr0;
      *(uint4*)&Vs[pn * 4608 + (srow + 32) * LDK + scol] = vr1;
    }
    p ^= 1;
  }

#pragma unroll
  for (int r = 0; r < 4; r++)
#pragma unroll
    for (int off = 1; off < 16; off <<= 1) ls[r] += __shfl_xor(ls[r], off);

  if (!heavy) {
#pragma unroll
    for (int r = 0; r < 4; r++) {
      float inv = 1.f / ls[r];
      size_t row = (size_t)b * SS + (size_t)l * 64 + w * 16 + quad * 4 + r;
#pragma unroll
      for (int tt = 0; tt < 4; tt++)
        ctxb[row * DD + h * HD + tt * 16 + lr] = f2bf(Ot[tt][r] * inv);
    }
  } else {
    float* pb = part + ((size_t)hid * 8 + chunk) * 4160;
#pragma unroll
    for (int r = 0; r < 4; r++) {
      int rowi = w * 16 + quad * 4 + r;
#pragma unroll
      for (int tt = 0; tt < 4; tt++)
        pb[rowi * 64 + tt * 16 + lr] = Ot[tt][r];
      if (lr == 0) pb[4096 + rowi] = ls[r];
    }
  }
}

__device__ __forceinline__ void reduce_one(int hid, const float* part,
                                           unsigned short* ctxb,
                                           unsigned short* smem, int tid) {
  float* lrow = (float*)smem;
  int b = hid / 24;
  int r = hid % 24;
  int h = r >> 1;
  int l = (r & 1) ? (NBK - 1) : 0;
  const float* pb = part + (size_t)hid * 8 * 4160;
  __syncthreads();
  if (tid < 64) {
    float s = 0.f;
#pragma unroll
    for (int c = 0; c < 8; c++) s += pb[c * 4160 + 4096 + tid];
    lrow[tid] = s;
  }
  __syncthreads();
  for (int e = tid; e < 4096; e += 256) {
    float o = 0.f;
#pragma unroll
    for (int c = 0; c < 8; c++) o += pb[c * 4160 + e];
    int rowi = e >> 6, col = e & 63;
    size_t row = (size_t)b * SS + (size_t)l * 64 + rowi;
    ctxb[row * DD + h * HD + col] = f2bf(o / lrow[rowi]);
  }
  __syncthreads();
}

__global__ __launch_bounds__(256) void fused_all(
    const float* __restrict__ hs, const float* __restrict__ Wq,
    const float* __restrict__ Wk, const float* __restrict__ Wv,
    const float* __restrict__ Wo, const int* __restrict__ graph,
    float* __restrict__ dst, unsigned short* __restrict__ wsu) {
  __shared__ __align__(16) unsigned short smem[24576];  // 48 KB union
  int tid = threadIdx.x;
  int wg = blockIdx.x;
  int gsz = gridDim.x;
  const size_t NHS = (size_t)BB * SS * DD;
  unsigned short* hsb = wsu;
  unsigned short* wqkvb = hsb + NHS;
  unsigned short* wob = wqkvb + 3 * 768 * 768;
  unsigned short* qb = wob + 768 * 768;
  unsigned short* kb = qb + NHS;
  unsigned short* vtb = kb + NHS;
  unsigned short* ctxb = vtb + NHS;
  float* part = (float*)(ctxb + NHS);
  cg::grid_group grid = cg::this_grid();

  // ---- phase 0: fp32 -> bf16 conversion ----
  for (long i4 = (long)wg * 256 + tid; i4 < 2162688; i4 += (long)gsz * 256) {
    const float* src;
    unsigned short* dp;
    if (i4 < 1572864) {
      src = hs + i4 * 4;
      dp = hsb + i4 * 4;
    } else {
      long r = i4 - 1572864;
      int wsel = (int)(r / 147456);
      long e = r % 147456;
      src = (wsel == 0 ? Wq : wsel == 1 ? Wk : wsel == 2 ? Wv : Wo) + e * 4;
      dp = (wsel < 3) ? (wqkvb + (long)wsel * 589824 + e * 4) : (wob + e * 4);
    }
    float4_t v = *(const float4_t*)src;
    uint2 pk;
    pk.x = (unsigned)f2bf(v[0]) | ((unsigned)f2bf(v[1]) << 16);
    pk.y = (unsigned)f2bf(v[2]) | ((unsigned)f2bf(v[3]) << 16);
    *(uint2*)dp = pk;
  }
  __threadfence();
  grid.sync();
  __threadfence();

  // ---- phase 1: QKV projection (2304 tiles) ----
  for (int vb = wg; vb < 2304; vb += gsz)
    qkv_tile(vb, hsb, wqkvb, qb, kb, vtb, smem, tid);
  __threadfence();
  grid.sync();
  __threadfence();

  // ---- phase 2: block-sparse attention (1872 virtual blocks) ----
  for (int vb = wg; vb < 1872; vb += gsz)
    attn_one(vb, qb, kb, vtb, graph, ctxb, part, smem, tid);
  __threadfence();
  grid.sync();
  __threadfence();

  // ---- phase 3: heavy-row reduction (48) ----
  for (int vb = wg; vb < 48; vb += gsz) reduce_one(vb, part, ctxb, smem, tid);
  __threadfence();
  grid.sync();
  __threadfence();

  // ---- phase 4: output projection (768 tiles) ----
  for (int vb = wg; vb < 768; vb += gsz)
    out_tile(vb, ctxb, wob, dst, smem, tid);
}

// ===========================================================================
// Fallback path: the proven round-6 5-kernel chain (used only if the
// cooperative launch is unavailable).
// ===========================================================================

__global__ __launch_bounds__(256) void cvt_all(
    const float* __restrict__ hs, const float* __restrict__ Wq,
    const float* __restrict__ Wk, const float* __restrict__ Wv,
    const float* __restrict__ Wo, unsigned short* __restrict__ hsb,
    unsigned short* __restrict__ wqkvb, unsigned short* __restrict__ wob) {
  long i4 = (long)blockIdx.x * 256 + threadIdx.x;
  const float* src;
  unsigned short* dst;
  if (i4 < 1572864) {
    src = hs + i4 * 4;
    dst = hsb + i4 * 4;
  } else {
    long r = i4 - 1572864;
    int w = (int)(r / 147456);
    long e = r % 147456;
    src = (w == 0 ? Wq : w == 1 ? Wk : w == 2 ? Wv : Wo) + e * 4;
    dst = (w < 3) ? (wqkvb + (long)w * 589824 + e * 4) : (wob + e * 4);
  }
  float4_t v = *(const float4_t*)src;
  uint2 p;
  p.x = (unsigned)f2bf(v[0]) | ((unsigned)f2bf(v[1]) << 16);
  p.y = (unsigned)f2bf(v[2]) | ((unsigned)f2bf(v[3]) << 16);
  *(uint2*)dst = p;
}

__global__ __launch_bounds__(256) void gemm_qkv_b(
    const unsigned short* __restrict__ A, const unsigned short* __restrict__ W,
    unsigned short* __restrict__ qb, unsigned short* __restrict__ kb,
    unsigned short* __restrict__ vtb) {
  __shared__ __align__(16) unsigned short smem[24576];
  int vb = blockIdx.x + blockIdx.y * 64;
  qkv_tile(vb, A, W, qb, kb, vtb, smem, threadIdx.x);
}

__global__ __launch_bounds__(256) void gemm_out_b(
    const unsigned short* __restrict__ A, const unsigned short* __restrict__ W,
    float* __restrict__ dst) {
  __shared__ __align__(16) unsigned short smem[24576];
  int vb = blockIdx.x + blockIdx.y * 64;
  out_tile(vb, A, W, dst, smem, threadIdx.x);
}

__global__ __launch_bounds__(256) void attn2(
    const unsigned short* __restrict__ q, const unsigned short* __restrict__ k,
    const unsigned short* __restrict__ vt, const int* __restrict__ graph,
    unsigned short* __restrict__ ctxb, float* __restrict__ part) {
  __shared__ __align__(16) unsigned short smem[24576];
  attn_one(blockIdx.x, q, k, vt, graph, ctxb, part, smem, threadIdx.x);
}

__global__ __launch_bounds__(256) void reduce_heavy(
    const float* __restrict__ part, unsigned short* __restrict__ ctxb) {
  __shared__ __align__(16) unsigned short smem[24576];
  reduce_one(blockIdx.x, part, ctxb, smem, threadIdx.x);
}

extern "C" void kernel_launch(void* const* d_in, const int* in_sizes, int n_in,
                              void* d_out, int out_size, void* d_ws,
                              size_t ws_size, hipStream_t stream) {
  const float* hs = (const float*)d_in[0];
  const float* Wq = (const float*)d_in[1];
  const float* Wk = (const float*)d_in[2];
  const float* Wv = (const float*)d_in[3];
  const float* Wo = (const float*)d_in[4];
  const int* graph = (const int*)d_in[10];
  unsigned short* wsu = (unsigned short*)d_ws;
  float* dst = (float*)d_out;

  int nb = 0;
  hipError_t oe =
      hipOccupancyMaxActiveBlocksPerMultiprocessor(&nb, fused_all, 256, 0);
  if (oe == hipSuccess && nb >= 1) {
    int gridn = nb * 256;  // 256 CUs on MI355X
    if (gridn > 2304) gridn = 2304;
    void* args[8];
    args[0] = (void*)&hs;
    args[1] = (void*)&Wq;
    args[2] = (void*)&Wk;
    args[3] = (void*)&Wv;
    args[4] = (void*)&Wo;
    args[5] = (void*)&graph;
    args[6] = (void*)&dst;
    args[7] = (void*)&wsu;
    hipError_t le = hipLaunchCooperativeKernel(
        (const void*)fused_all, dim3(gridn, 1, 1), dim3(256, 1, 1), args, 0,
        stream);
    if (le == hipSuccess) return;
  }

  // fallback: proven 5-kernel chain
  const size_t NHS = (size_t)BB * SS * DD;
  unsigned short* hsb = wsu;
  unsigned short* wqkvb = hsb + NHS;
  unsigned short* wob = wqkvb + 3 * 768 * 768;
  unsigned short* qb = wob + 768 * 768;
  unsigned short* kb = qb + NHS;
  unsigned short* vtb = kb + NHS;
  unsigned short* ctxb = vtb + NHS;
  float* part = (float*)(ctxb + NHS);

  cvt_all<<<8448, 256, 0, stream>>>(hs, Wq, Wk, Wv, Wo, hsb, wqkvb, wob);
  gemm_qkv_b<<<dim3(64, 36, 1), 256, 0, stream>>>(hsb, wqkvb, qb, kb, vtb);
  attn2<<<1872, 256, 0, stream>>>(qb, kb, vtb, graph, ctxb, part);
  reduce_heavy<<<48, 256, 0, stream>>>(part, ctxb);
  gemm_out_b<<<dim3(64, 12, 1), 256, 0, stream>>>(ctxb, wob, dst);
}